// Round 24
// baseline (541.330 us; speedup 1.0000x reference)
//
#include <hip/hip_runtime.h>
#include <math.h>

typedef unsigned short u16;
typedef unsigned int   u32;
typedef __attribute__((ext_vector_type(8))) short short8;
typedef __attribute__((ext_vector_type(4))) float f32x4;

#define NPTS 4096
#define NB   16
#define FLT_BIG 3.402823466e38f

// ---- workspace layout (float offsets), total ~155 MB ----
// y1 tiles (2-plane): per (b,nt,kt) 8192 u16 [plane2][kot4][n128][8k]
// y2 tiles (1-plane): per (b,nt,kt) 4096 u16 [kot4][n128][8k]
static const size_t OFF_Y1T = 0;          // 33,554,432 u16 (64 MB)
static const size_t OFF_Y2T = 16777216;   // 33,554,432 u16 (64 MB)
static const size_t OFF_W1I = 33554432;   // 344064 u16
static const size_t OFF_W2I = 33726464;   // 262144 u16
static const size_t OFF_W3I = 33857536;   // 1048576 u16
static const size_t OFF_PS  = 34381824;
static const size_t OFF_PQ  = 35430400;
static const size_t OFF_PMX = 36478976;
static const size_t OFF_PMN = 37527552;
static const size_t OFF_ASH = 38576128;   // float2[1024]

__device__ __forceinline__ void gload_lds16(const void* g, void* l) {
    __builtin_amdgcn_global_load_lds(
        (const __attribute__((address_space(1))) u32*)g,
        (__attribute__((address_space(3))) u32*)l, 16, 0, 0);
}
__device__ __forceinline__ u32 pk(u32 a, u32 b) {   // mem order [a.hi16, b.hi16]
    return __builtin_amdgcn_perm(b, a, 0x07060302u);
}
#define MFM(a, b, c) __builtin_amdgcn_mfma_f32_16x16x32_bf16(a, b, c, 0, 0, 0)

// ---- W prep (2-plane hi+mid): L1 128-chunks, L2/L3 256-chunks ----
__global__ __launch_bounds__(256) void prep_w(const float* __restrict__ W1,
                                              const float* __restrict__ W2,
                                              const float* __restrict__ W3,
                                              u16* __restrict__ w1i,
                                              u16* __restrict__ w2i,
                                              u16* __restrict__ w3i) {
    const int bx = blockIdx.x;
    if (bx < 42) {
        const int mc = bx / 21, kt = bx % 21;
        u16* tb = w1i + ((size_t)(mc * 21 + kt) << 13);
#pragma unroll
        for (int it = 0; it < 2; ++it) {
            const int item = it * 256 + threadIdx.x;
            const int m = item & 127, kot = item >> 7;
            const int k0 = kt * 32 + kot * 8;
            const float* wr = W1 + (size_t)(mc * 128 + m) * 643;
            u32 hh[8], mm[8];
#pragma unroll
            for (int j = 0; j < 8; ++j) {
                const int k = k0 + j;
                const float x = (k < 643) ? wr[k] : 0.f;
                const u32 u = __float_as_uint(x);
                const u32 uh = u + 0x8000u;
                const float r1 = x - __uint_as_float(uh & 0xFFFF0000u);
                hh[j] = uh;
                mm[j] = __float_as_uint(r1) + 0x8000u;
            }
            uint4 wh, wmv;
            wh.x = pk(hh[0], hh[1]); wh.y = pk(hh[2], hh[3]);
            wh.z = pk(hh[4], hh[5]); wh.w = pk(hh[6], hh[7]);
            wmv.x = pk(mm[0], mm[1]); wmv.y = pk(mm[2], mm[3]);
            wmv.z = pk(mm[4], mm[5]); wmv.w = pk(mm[6], mm[7]);
            u16* dst = tb + kot * 1024 + m * 8;
            *(uint4*)dst          = wh;
            *(uint4*)(dst + 4096) = wmv;
        }
    } else {
        const float* W; u16* img; int Kact, KT, mc, kt;
        if (bx < 58) { W = W2; img = w2i; Kact = 256; KT = 8;  const int t = bx - 42; mc = t >> 3; kt = t & 7; }
        else         { W = W3; img = w3i; Kact = 512; KT = 16; const int t = bx - 58; mc = t >> 4; kt = t & 15; }
        u16* tb = img + ((size_t)(mc * KT + kt) << 14);
#pragma unroll
        for (int it = 0; it < 4; ++it) {
            const int item = it * 256 + threadIdx.x;
            const int m = item & 255, kot = item >> 8;
            const int k0 = kt * 32 + kot * 8;
            const float* wr = W + (size_t)(mc * 256 + m) * Kact;
            u32 hh[8], mm[8];
#pragma unroll
            for (int j = 0; j < 8; ++j) {
                const int k = k0 + j;
                const float x = (k < Kact) ? wr[k] : 0.f;
                const u32 u = __float_as_uint(x);
                const u32 uh = u + 0x8000u;
                const float r1 = x - __uint_as_float(uh & 0xFFFF0000u);
                hh[j] = uh;
                mm[j] = __float_as_uint(r1) + 0x8000u;
            }
            uint4 wh, wmv;
            wh.x = pk(hh[0], hh[1]); wh.y = pk(hh[2], hh[3]);
            wh.z = pk(hh[4], hh[5]); wh.w = pk(hh[6], hh[7]);
            wmv.x = pk(mm[0], mm[1]); wmv.y = pk(mm[2], mm[3]);
            wmv.z = pk(mm[4], mm[5]); wmv.w = pk(mm[6], mm[7]);
            u16* dst = tb + kot * 2048 + m * 8;
            *(uint4*)dst          = wh;
            *(uint4*)(dst + 8192) = wmv;
        }
    }
}

// ---- bnfix2: in-place BN+ReLU on 2-plane tiles (y1) ----
__global__ __launch_bounds__(256) void bnfix2(u16* __restrict__ yt, int KT,
                                              const float2* __restrict__ ash) {
    const int kt = blockIdx.x, nt = blockIdx.y, b = blockIdx.z;
    u16* tb = yt + ((size_t)((b * 32 + nt) * KT + kt) << 13);
    const int n = threadIdx.x & 127, kh = threadIdx.x >> 7;
#pragma unroll
    for (int q = 0; q < 2; ++q) {
        const int kot = kh * 2 + q;
        u16* ph = tb + kot * 1024 + n * 8;
        uint4 H  = *(uint4*)ph;
        uint4 Mv = *(uint4*)(ph + 4096);
        u32 hw[4] = {H.x, H.y, H.z, H.w};
        u32 mw[4] = {Mv.x, Mv.y, Mv.z, Mv.w};
        u32 oh[4], om[4];
#pragma unroll
        for (int wi = 0; wi < 4; ++wi) {
            u32 uh2[2], um2[2];
#pragma unroll
            for (int e = 0; e < 2; ++e) {
                const u32 hb = e ? (hw[wi] & 0xFFFF0000u) : (hw[wi] << 16);
                const u32 mb = e ? (mw[wi] & 0xFFFF0000u) : (mw[wi] << 16);
                const float x = __uint_as_float(hb) + __uint_as_float(mb);
                const int k = kt * 32 + kot * 8 + wi * 2 + e;
                const float2 a = ash[k];
                const float y = fmaxf(fmaf(a.x, x, a.y), 0.f);
                const u32 uy = __float_as_uint(y) + 0x8000u;
                const float r1 = y - __uint_as_float(uy & 0xFFFF0000u);
                uh2[e] = uy;
                um2[e] = __float_as_uint(r1) + 0x8000u;
            }
            oh[wi] = pk(uh2[0], uh2[1]);
            om[wi] = pk(um2[0], um2[1]);
        }
        *(uint4*)ph          = make_uint4(oh[0], oh[1], oh[2], oh[3]);
        *(uint4*)(ph + 4096) = make_uint4(om[0], om[1], om[2], om[3]);
    }
}

// ---- bnfix1: in-place BN+ReLU on single-plane bf16 tiles (y2) ----
__global__ __launch_bounds__(256) void bnfix1(u16* __restrict__ yt, int KT,
                                              const float2* __restrict__ ash) {
    const int kt = blockIdx.x, nt = blockIdx.y, b = blockIdx.z;
    u16* tb = yt + ((size_t)((b * 32 + nt) * KT + kt) << 12);
    const int n = threadIdx.x & 127, kh = threadIdx.x >> 7;
#pragma unroll
    for (int q = 0; q < 2; ++q) {
        const int kot = kh * 2 + q;
        u16* ph = tb + kot * 1024 + n * 8;
        uint4 H = *(uint4*)ph;
        u32 hw[4] = {H.x, H.y, H.z, H.w};
        u32 oh[4];
#pragma unroll
        for (int wi = 0; wi < 4; ++wi) {
            u32 uh2[2];
#pragma unroll
            for (int e = 0; e < 2; ++e) {
                const u32 hb = e ? (hw[wi] & 0xFFFF0000u) : (hw[wi] << 16);
                const float x = __uint_as_float(hb);
                const int k = kt * 32 + kot * 8 + wi * 2 + e;
                const float2 a = ash[k];
                const float y = fmaxf(fmaf(a.x, x, a.y), 0.f);
                uh2[e] = __float_as_uint(y) + 0x8000u;
            }
            oh[wi] = pk(uh2[0], uh2[1]);
        }
        *(uint4*)ph = make_uint4(oh[0], oh[1], oh[2], oh[3]);
    }
}

// ================= L1 GEMM (fp32 B, 3-product, 128^2, dbuf; writes 2-plane y1) =================
__global__ __launch_bounds__(256)
void gemm_L1(const u16* __restrict__ Wimg, int KT, int Kact, int M_,
             const float* __restrict__ bias, const float* __restrict__ X,
             u16* __restrict__ Yt, int YKT,
             float* __restrict__ psum, float* __restrict__ psq)
{
    __shared__ __align__(16) u16 As_[2 * 8192];
    __shared__ __align__(16) u16 Bs_[2 * 8192];
    const int tid = threadIdx.x;
    const int lane = tid & 63, wid = tid >> 6;
    const int l15 = lane & 15, l4 = lane >> 4;
    const int wm = wid >> 1, wn = wid & 1;
    const int nt = blockIdx.x, mtb = blockIdx.y, b = blockIdx.z;
    const int m0 = mtb * 128, n0 = nt * 128;
    const int nb = tid & 127, kh = tid >> 7;
    f32x4 acc[4][4];
#pragma unroll
    for (int i = 0; i < 4; ++i)
#pragma unroll
        for (int j = 0; j < 4; ++j) acc[i][j] = (f32x4){0.f, 0.f, 0.f, 0.f};
    const u16* wtile = Wimg + ((size_t)mtb * KT << 13);
    const int afo = l4 * 1024 + (wm * 64 + l15) * 8;
    const int bfo = l4 * 1024 + (wn * 64 + l15) * 8;
    float xr[16];

#define L1_STAGE_A(kt, buf)                                                       \
    {                                                                             \
        const u16* g_ = wtile + ((size_t)(kt) << 13);                             \
        u16* l_ = As_ + ((buf) << 13);                                            \
        _Pragma("unroll")                                                         \
        for (int i_ = 0; i_ < 4; ++i_)                                            \
            gload_lds16(g_ + (wid * 4 + i_) * 512 + lane * 8,                     \
                        l_ + (wid * 4 + i_) * 512);                               \
    }
#define L1_READ_B(kt)                                                             \
    {                                                                             \
        const int kb_ = (kt) * 32 + kh * 16;                                      \
        const float* src_ = X + ((size_t)b * Kact + kb_) * NPTS + n0 + nb;        \
        _Pragma("unroll")                                                         \
        for (int j_ = 0; j_ < 16; ++j_)                                           \
            xr[j_] = (kb_ + j_ < Kact) ? src_[(size_t)j_ * NPTS] : 0.f;           \
    }
#define L1_WRITE_B(buf)                                                           \
    {                                                                             \
        u32 hh_[16], mm_[16];                                                     \
        _Pragma("unroll")                                                         \
        for (int j_ = 0; j_ < 16; ++j_) {                                         \
            const float x_ = xr[j_];                                              \
            const u32 u_ = __float_as_uint(x_);                                   \
            const u32 uh_ = u_ + 0x8000u;                                         \
            const float r1_ = x_ - __uint_as_float(uh_ & 0xFFFF0000u);            \
            hh_[j_] = uh_;                                                        \
            mm_[j_] = __float_as_uint(r1_) + 0x8000u;                             \
        }                                                                         \
        u16* bb_ = Bs_ + ((buf) << 13);                                           \
        _Pragma("unroll")                                                         \
        for (int q_ = 0; q_ < 2; ++q_) {                                          \
            uint4 wh_, wm_;                                                       \
            wh_.x = pk(hh_[q_*8+0], hh_[q_*8+1]); wh_.y = pk(hh_[q_*8+2], hh_[q_*8+3]); \
            wh_.z = pk(hh_[q_*8+4], hh_[q_*8+5]); wh_.w = pk(hh_[q_*8+6], hh_[q_*8+7]); \
            wm_.x = pk(mm_[q_*8+0], mm_[q_*8+1]); wm_.y = pk(mm_[q_*8+2], mm_[q_*8+3]); \
            wm_.z = pk(mm_[q_*8+4], mm_[q_*8+5]); wm_.w = pk(mm_[q_*8+6], mm_[q_*8+7]); \
            const int kot_ = kh * 2 + q_;                                         \
            *(uint4*)(bb_ + kot_ * 1024 + nb * 8)        = wh_;                   \
            *(uint4*)(bb_ + 4096 + kot_ * 1024 + nb * 8) = wm_;                   \
        }                                                                         \
    }
#define L1_COMPUTE(buf)                                                           \
    {                                                                             \
        const u16* A_ = As_ + ((buf) << 13);                                      \
        const u16* B_ = Bs_ + ((buf) << 13);                                      \
        short8 ah_[4], am_[4];                                                    \
        _Pragma("unroll")                                                         \
        for (int mf_ = 0; mf_ < 4; ++mf_) {                                       \
            ah_[mf_] = *(const short8*)(A_ + afo + mf_ * 128);                    \
            am_[mf_] = *(const short8*)(A_ + 4096 + afo + mf_ * 128);             \
        }                                                                         \
        _Pragma("unroll")                                                         \
        for (int nf_ = 0; nf_ < 4; ++nf_) {                                       \
            const short8 bh_ = *(const short8*)(B_ + bfo + nf_ * 128);            \
            const short8 bm_ = *(const short8*)(B_ + 4096 + bfo + nf_ * 128);     \
            _Pragma("unroll")                                                     \
            for (int mf_ = 0; mf_ < 4; ++mf_)                                     \
                acc[mf_][nf_] = MFM(ah_[mf_], bh_, acc[mf_][nf_]);                \
            _Pragma("unroll")                                                     \
            for (int mf_ = 0; mf_ < 4; ++mf_)                                     \
                acc[mf_][nf_] = MFM(ah_[mf_], bm_, acc[mf_][nf_]);                \
            _Pragma("unroll")                                                     \
            for (int mf_ = 0; mf_ < 4; ++mf_)                                     \
                acc[mf_][nf_] = MFM(am_[mf_], bh_, acc[mf_][nf_]);                \
        }                                                                         \
    }

    int o = 0;
    L1_READ_B(0);
    L1_STAGE_A(0, 0);
    L1_WRITE_B(0);
    __syncthreads();
    for (int kt = 0; kt < KT; ++kt) {
        if (kt + 1 < KT) {
            L1_READ_B(kt + 1);
            L1_STAGE_A(kt + 1, o ^ 1);
        }
        L1_COMPUTE(o);
        if (kt + 1 < KT) { L1_WRITE_B(o ^ 1); }
        __syncthreads();
        o ^= 1;
    }

    u16* ytb = Yt + ((size_t)((b * 32 + nt) * YKT) << 13);
#pragma unroll
    for (int mf = 0; mf < 4; ++mf) {
        const int kb = m0 + wm * 64 + mf * 16 + l4 * 4;
        float v4[4][4];
#pragma unroll
        for (int r = 0; r < 4; ++r) {
            const int m = kb + r;
            const float bvv = bias[m];
            float rs = 0.f, rq = 0.f;
#pragma unroll
            for (int nf = 0; nf < 4; ++nf) {
                const float v = acc[mf][nf][r] + bvv;
                v4[r][nf] = v; rs += v; rq = fmaf(v, v, rq);
            }
#pragma unroll
            for (int s = 1; s < 16; s <<= 1) {
                rs += __shfl_xor(rs, s);
                rq += __shfl_xor(rq, s);
            }
            if (l15 == 0) {
                const int slot = (b * 32 + nt) * 2 + wn;
                psum[(size_t)slot * M_ + m] = rs;
                psq[(size_t)slot * M_ + m]  = rq;
            }
        }
        {
            const int ktp = kb >> 5, kot = (kb >> 3) & 3, j0 = kb & 7;
            u16* dt = ytb + ((size_t)ktp << 13) + kot * 1024 + j0;
#pragma unroll
            for (int nf = 0; nf < 4; ++nf) {
                const int nwi = wn * 64 + nf * 16 + l15;
                u32 uh[4], um[4];
#pragma unroll
                for (int r = 0; r < 4; ++r) {
                    const float v = v4[r][nf];
                    const u32 a = __float_as_uint(v) + 0x8000u;
                    const float r1 = v - __uint_as_float(a & 0xFFFF0000u);
                    uh[r] = a;
                    um[r] = __float_as_uint(r1) + 0x8000u;
                }
                uint2 wh2; wh2.x = pk(uh[0], uh[1]); wh2.y = pk(uh[2], uh[3]);
                uint2 wm2; wm2.x = pk(um[0], um[1]); wm2.y = pk(um[2], um[3]);
                *(uint2*)(dt + nwi * 8)        = wh2;
                *(uint2*)(dt + 4096 + nwi * 8) = wm2;
            }
        }
    }
}

// ================= 8-phase 256^2 kernels =================
#define G8_PARAMS                                                                 \
    const u16* __restrict__ Wimg, int KT, int M_,                                 \
    const float* __restrict__ bias,                                               \
    const u16* __restrict__ Bt,                                                   \
    u16* __restrict__ Yt, int YKT,                                                \
    float* __restrict__ psum, float* __restrict__ psq,                            \
    float* __restrict__ pmax, float* __restrict__ pmin

#define STAGE_A8(kt, buf)                                                         \
    {                                                                             \
        const u16* g_ = wtile + ((size_t)(kt) << 14);                             \
        u16* l_ = As_ + ((buf) << 14);                                            \
        _Pragma("unroll")                                                         \
        for (int i_ = 0; i_ < 4; ++i_)                                            \
            gload_lds16(g_ + (wid * 4 + i_) * 512 + lane * 8,                     \
                        l_ + (wid * 4 + i_) * 512);                               \
    }
#define STAGE_B8_3P(kt, buf)                                                      \
    {                                                                             \
        const u16* g_ = btw + ((size_t)(kt) << 13);                               \
        u16* l_ = Bs_ + ((buf) << 14) + (wm << 13);                               \
        _Pragma("unroll")                                                         \
        for (int i_ = 0; i_ < 4; ++i_)                                            \
            gload_lds16(g_ + (wn * 4 + i_) * 512 + lane * 8,                      \
                        l_ + (wn * 4 + i_) * 512);                                \
    }
#define STAGE_B8_2P(kt, buf)                                                      \
    {                                                                             \
        const u16* g_ = btw + ((size_t)(kt) << 12);                               \
        u16* l_ = Bs_ + ((buf) << 13) + (wm << 12);                               \
        _Pragma("unroll")                                                         \
        for (int i_ = 0; i_ < 2; ++i_)                                            \
            gload_lds16(g_ + (wn * 2 + i_) * 512 + lane * 8,                      \
                        l_ + (wn * 2 + i_) * 512);                                \
    }

#define MFMA_BLK(q, a0, a1, B0, B1, B2, B3)                                       \
        acc[2*(q)][0]   = MFM(a0, B0, acc[2*(q)][0]);                             \
        acc[2*(q)+1][0] = MFM(a1, B0, acc[2*(q)+1][0]);                           \
        acc[2*(q)][1]   = MFM(a0, B1, acc[2*(q)][1]);                             \
        acc[2*(q)+1][1] = MFM(a1, B1, acc[2*(q)+1][1]);                           \
        acc[2*(q)][2]   = MFM(a0, B2, acc[2*(q)][2]);                             \
        acc[2*(q)+1][2] = MFM(a1, B2, acc[2*(q)+1][2]);                           \
        acc[2*(q)][3]   = MFM(a0, B3, acc[2*(q)][3]);                             \
        acc[2*(q)+1][3] = MFM(a1, B3, acc[2*(q)+1][3]);

// ---- L2: 2 half-phases/kt, 48 MFMA/phase (3-product). Stage A+B at p0; vmcnt at p1. ----
// Per acc element the product order stays hh -> hm -> mh (bitwise-identical accumulation).
#define PHASE2_3P(p, CUR, NXT, kt)                                                \
    {                                                                             \
        const u16* A_ = As_ + ((CUR) << 14);                                      \
        short8 a0h = *(const short8*)(A_ + aof + (4 * (p) + 0) * 128);            \
        short8 a1h = *(const short8*)(A_ + aof + (4 * (p) + 1) * 128);            \
        short8 a2h = *(const short8*)(A_ + aof + (4 * (p) + 2) * 128);            \
        short8 a3h = *(const short8*)(A_ + aof + (4 * (p) + 3) * 128);            \
        short8 a0m = *(const short8*)(A_ + 8192 + aof + (4 * (p) + 0) * 128);     \
        short8 a1m = *(const short8*)(A_ + 8192 + aof + (4 * (p) + 1) * 128);     \
        short8 a2m = *(const short8*)(A_ + 8192 + aof + (4 * (p) + 2) * 128);     \
        short8 a3m = *(const short8*)(A_ + 8192 + aof + (4 * (p) + 3) * 128);     \
        if ((p) == 0) {                                                           \
            const u16* B_ = Bs_ + ((CUR) << 14) + bof;                            \
            bh0 = *(const short8*)(B_);                                           \
            bh1 = *(const short8*)(B_ + 128);                                     \
            bh2 = *(const short8*)(B_ + 256);                                     \
            bh3 = *(const short8*)(B_ + 384);                                     \
            bm0 = *(const short8*)(B_ + 4096);                                    \
            bm1 = *(const short8*)(B_ + 4096 + 128);                              \
            bm2 = *(const short8*)(B_ + 4096 + 256);                              \
            bm3 = *(const short8*)(B_ + 4096 + 384);                              \
        }                                                                         \
        if ((p) == 0 && (kt) + 1 < KT) {                                          \
            STAGE_A8((kt) + 1, NXT);                                              \
            STAGE_B8_3P((kt) + 1, NXT);                                           \
        }                                                                         \
        if ((p) == 1) { asm volatile("s_waitcnt vmcnt(0)" ::: "memory"); }        \
        __builtin_amdgcn_sched_barrier(0);                                        \
        __builtin_amdgcn_s_barrier();                                             \
        asm volatile("s_waitcnt lgkmcnt(0)" ::: "memory");                        \
        __builtin_amdgcn_sched_barrier(0);                                        \
        __builtin_amdgcn_s_setprio(1);                                            \
        MFMA_BLK(2*(p),     a0h, a1h, bh0, bh1, bh2, bh3)                         \
        MFMA_BLK(2*(p) + 1, a2h, a3h, bh0, bh1, bh2, bh3)                         \
        MFMA_BLK(2*(p),     a0h, a1h, bm0, bm1, bm2, bm3)                         \
        MFMA_BLK(2*(p) + 1, a2h, a3h, bm0, bm1, bm2, bm3)                         \
        MFMA_BLK(2*(p),     a0m, a1m, bh0, bh1, bh2, bh3)                         \
        MFMA_BLK(2*(p) + 1, a2m, a3m, bh0, bh1, bh2, bh3)                         \
        __builtin_amdgcn_s_setprio(0);                                            \
    }

// ---- L3: 2 half-phases/kt, 32 MFMA/phase (2-product). Stage A+B at p0; vmcnt at p1. ----
#define PHASE2_2P(p, CUR, NXT, kt)                                                \
    {                                                                             \
        const u16* A_ = As_ + ((CUR) << 14);                                      \
        short8 a0h = *(const short8*)(A_ + aof + (4 * (p) + 0) * 128);            \
        short8 a1h = *(const short8*)(A_ + aof + (4 * (p) + 1) * 128);            \
        short8 a2h = *(const short8*)(A_ + aof + (4 * (p) + 2) * 128);            \
        short8 a3h = *(const short8*)(A_ + aof + (4 * (p) + 3) * 128);            \
        short8 a0m = *(const short8*)(A_ + 8192 + aof + (4 * (p) + 0) * 128);     \
        short8 a1m = *(const short8*)(A_ + 8192 + aof + (4 * (p) + 1) * 128);     \
        short8 a2m = *(const short8*)(A_ + 8192 + aof + (4 * (p) + 2) * 128);     \
        short8 a3m = *(const short8*)(A_ + 8192 + aof + (4 * (p) + 3) * 128);     \
        if ((p) == 0) {                                                           \
            const u16* B_ = Bs_ + ((CUR) << 13) + bof;                            \
            bh0 = *(const short8*)(B_);                                           \
            bh1 = *(const short8*)(B_ + 128);                                     \
            bh2 = *(const short8*)(B_ + 256);                                     \
            bh3 = *(const short8*)(B_ + 384);                                     \
        }                                                                         \
        if ((p) == 0 && (kt) + 1 < KT) {                                          \
            STAGE_A8((kt) + 1, NXT);                                              \
            STAGE_B8_2P((kt) + 1, NXT);                                           \
        }                                                                         \
        if ((p) == 1) { asm volatile("s_waitcnt vmcnt(0)" ::: "memory"); }        \
        __builtin_amdgcn_sched_barrier(0);                                        \
        __builtin_amdgcn_s_barrier();                                             \
        asm volatile("s_waitcnt lgkmcnt(0)" ::: "memory");                        \
        __builtin_amdgcn_sched_barrier(0);                                        \
        __builtin_amdgcn_s_setprio(1);                                            \
        MFMA_BLK(2*(p),     a0h, a1h, bh0, bh1, bh2, bh3)                         \
        MFMA_BLK(2*(p) + 1, a2h, a3h, bh0, bh1, bh2, bh3)                         \
        MFMA_BLK(2*(p),     a0m, a1m, bh0, bh1, bh2, bh3)                         \
        MFMA_BLK(2*(p) + 1, a2m, a3m, bh0, bh1, bh2, bh3)                         \
        __builtin_amdgcn_s_setprio(0);                                            \
    }

#define G8_EPILOGUE(STOREP, MAXMIN)                                               \
    _Pragma("unroll")                                                             \
    for (int mf = 0; mf < 8; ++mf) {                                              \
        const int mbase = mtb * 256 + wm * 128 + mf * 16 + l4 * 4;                \
        float v4[4][4];                                                           \
        _Pragma("unroll")                                                         \
        for (int r = 0; r < 4; ++r) {                                             \
            const int m = mbase + r;                                              \
            const float bvv = bias[m];                                            \
            float rs = 0.f, rq = 0.f;                                             \
            _Pragma("unroll")                                                     \
            for (int nf = 0; nf < 4; ++nf) {                                      \
                const float v = acc[mf][nf][r] + bvv;                             \
                v4[r][nf] = v; rs += v; rq = fmaf(v, v, rq);                      \
            }                                                                     \
            float mx = 0.f, mn = 0.f;                                             \
            if (MAXMIN) {                                                         \
                mx = fmaxf(fmaxf(v4[r][0], v4[r][1]), fmaxf(v4[r][2], v4[r][3])); \
                mn = fminf(fminf(v4[r][0], v4[r][1]), fminf(v4[r][2], v4[r][3])); \
            }                                                                     \
            _Pragma("unroll")                                                     \
            for (int s = 1; s < 16; s <<= 1) {                                    \
                rs += __shfl_xor(rs, s);                                          \
                rq += __shfl_xor(rq, s);                                          \
                if (MAXMIN) {                                                     \
                    mx = fmaxf(mx, __shfl_xor(mx, s));                            \
                    mn = fminf(mn, __shfl_xor(mn, s));                            \
                }                                                                 \
            }                                                                     \
            if (l15 == 0) {                                                       \
                const int slot = (b * 16 + ntb) * 4 + wn;                         \
                psum[(size_t)slot * M_ + m] = rs;                                 \
                psq[(size_t)slot * M_ + m]  = rq;                                 \
                if (MAXMIN) {                                                     \
                    pmax[((size_t)b * M_ + m) * 64 + ntb * 4 + wn] = mx;          \
                    pmin[((size_t)b * M_ + m) * 64 + ntb * 4 + wn] = mn;          \
                }                                                                 \
            }                                                                     \
        }                                                                         \
        if (STOREP) {                                                             \
            const int ktp = mbase >> 5, kot = (mbase >> 3) & 3, j0 = mbase & 7;   \
            u16* dt = ytb + ((size_t)ktp << 12) + kot * 1024 + j0;                \
            _Pragma("unroll")                                                     \
            for (int nf = 0; nf < 4; ++nf) {                                      \
                const int nwi = (wn & 1) * 64 + nf * 16 + l15;                    \
                u32 uh[4];                                                        \
                _Pragma("unroll")                                                 \
                for (int r = 0; r < 4; ++r)                                       \
                    uh[r] = __float_as_uint(v4[r][nf]) + 0x8000u;                 \
                uint2 wh2; wh2.x = pk(uh[0], uh[1]); wh2.y = pk(uh[2], uh[3]);    \
                *(uint2*)(dt + nwi * 8) = wh2;                                    \
            }                                                                     \
        }                                                                         \
    }

// L2: 3-product, 2-plane B (y1); 2 half-phases/kt; stores y2 single-plane
__global__ __launch_bounds__(512) void gemm8p_L2(G8_PARAMS)
{
    __shared__ __align__(16) u16 As_[2 * 16384];
    __shared__ __align__(16) u16 Bs_[2 * 16384];
    const int tid = threadIdx.x;
    const int lane = tid & 63, wid = tid >> 6;
    const int l15 = lane & 15, l4 = lane >> 4;
    const int wm = wid >> 2, wn = wid & 3;
    const int ntb = blockIdx.x, mtb = blockIdx.y, b = blockIdx.z;
    f32x4 acc[8][4];
#pragma unroll
    for (int i = 0; i < 8; ++i)
#pragma unroll
        for (int j = 0; j < 4; ++j) acc[i][j] = (f32x4){0.f, 0.f, 0.f, 0.f};
    const u16* wtile = Wimg + ((size_t)(mtb * KT) << 14);
    const u16* btw = Bt + ((size_t)((b * 32 + ntb * 2 + wm) * KT) << 13);
    const int aof = l4 * 2048 + (wm * 128 + l15) * 8;
    const int bof = (wn >> 1) * 8192 + l4 * 1024 + ((wn & 1) * 64 + l15) * 8;
    short8 bh0, bh1, bh2, bh3, bm0, bm1, bm2, bm3;
    STAGE_A8(0, 0)
    STAGE_B8_3P(0, 0)
    asm volatile("s_waitcnt vmcnt(0)" ::: "memory");
    __builtin_amdgcn_s_barrier();
    for (int kt = 0; kt < KT; kt += 2) {
        PHASE2_3P(0, 0, 1, kt) PHASE2_3P(1, 0, 1, kt)
        PHASE2_3P(0, 1, 0, kt + 1) PHASE2_3P(1, 1, 0, kt + 1)
    }
    u16* ytb = Yt + ((size_t)((b * 32 + ntb * 2 + (wn >> 1)) * YKT) << 12);
    G8_EPILOGUE(true, false)
}

// L3: 2-product, 1-plane B (y2); 2 half-phases/kt; max/min partials, no store
__global__ __launch_bounds__(512) void gemm8p_L3(G8_PARAMS)
{
    __shared__ __align__(16) u16 As_[2 * 16384];
    __shared__ __align__(16) u16 Bs_[2 * 8192];
    const int tid = threadIdx.x;
    const int lane = tid & 63, wid = tid >> 6;
    const int l15 = lane & 15, l4 = lane >> 4;
    const int wm = wid >> 2, wn = wid & 3;
    const int ntb = blockIdx.x, mtb = blockIdx.y, b = blockIdx.z;
    f32x4 acc[8][4];
#pragma unroll
    for (int i = 0; i < 8; ++i)
#pragma unroll
        for (int j = 0; j < 4; ++j) acc[i][j] = (f32x4){0.f, 0.f, 0.f, 0.f};
    const u16* wtile = Wimg + ((size_t)(mtb * KT) << 14);
    const u16* btw = Bt + ((size_t)((b * 32 + ntb * 2 + wm) * KT) << 12);
    const int aof = l4 * 2048 + (wm * 128 + l15) * 8;
    const int bof = (wn >> 1) * 4096 + l4 * 1024 + ((wn & 1) * 64 + l15) * 8;
    short8 bh0, bh1, bh2, bh3;
    STAGE_A8(0, 0)
    STAGE_B8_2P(0, 0)
    asm volatile("s_waitcnt vmcnt(0)" ::: "memory");
    __builtin_amdgcn_s_barrier();
    for (int kt = 0; kt < KT; kt += 2) {
        PHASE2_2P(0, 0, 1, kt) PHASE2_2P(1, 0, 1, kt)
        PHASE2_2P(0, 1, 0, kt + 1) PHASE2_2P(1, 1, 0, kt + 1)
    }
    u16* ytb = nullptr;
    G8_EPILOGUE(false, true)
}

// ---- per-channel stats (1024 slots) -> BN scale/shift ----
__global__ __launch_bounds__(256) void stats_k(const float* __restrict__ psum, const float* __restrict__ psq,
                                               int M_,
                                               const float* __restrict__ g, const float* __restrict__ be,
                                               float2* __restrict__ ash)
{
    __shared__ double ds[4][64];
    __shared__ double dq[4][64];
    const int mloc = threadIdx.x & 63, q = threadIdx.x >> 6;
    const int m = blockIdx.x * 64 + mloc;
    double s = 0.0, sq = 0.0;
    for (int sl = q * 256; sl < (q + 1) * 256; ++sl) {
        s  += (double)psum[(size_t)sl * M_ + m];
        sq += (double)psq[(size_t)sl * M_ + m];
    }
    ds[q][mloc] = s; dq[q][mloc] = sq;
    __syncthreads();
    if (threadIdx.x < 64) {
        const double S = ds[0][mloc] + ds[1][mloc] + ds[2][mloc] + ds[3][mloc];
        const double Q = dq[0][mloc] + dq[1][mloc] + dq[2][mloc] + dq[3][mloc];
        const double cnt = (double)NB * (double)NPTS;
        double mean = S / cnt;
        double var  = Q / cnt - mean * mean;
        if (var < 0.0) var = 0.0;
        const double a = (double)g[m] / sqrt(var + 1e-5);
        ash[m] = make_float2((float)a, (float)((double)be[m] - a * mean));
    }
}

// ---- final: fused L3-stats, pool-select, BN-apply+ReLU, BN1d ----
__global__ __launch_bounds__(256) void final_k(const float* __restrict__ psum, const float* __restrict__ psq,
                                               const float* __restrict__ g3, const float* __restrict__ be3,
                                               const float* __restrict__ pmax, const float* __restrict__ pmin,
                                               const float* __restrict__ g4, const float* __restrict__ be4,
                                               float* __restrict__ out)
{
    const int c = blockIdx.x * 256 + threadIdx.x;
    if (c >= 1024) return;
    double S = 0.0, Q = 0.0;
    for (int sl = 0; sl < 1024; ++sl) {
        S += (double)psum[(size_t)sl * 1024 + c];
        Q += (double)psq[(size_t)sl * 1024 + c];
    }
    const double cnt = (double)NB * (double)NPTS;
    double mean3 = S / cnt;
    double var3  = Q / cnt - mean3 * mean3;
    if (var3 < 0.0) var3 = 0.0;
    const double a3 = (double)g3[c] / sqrt(var3 + 1e-5);
    const float a = (float)a3;
    const float sh = (float)((double)be3[c] - a3 * mean3);

    float h[NB];
    float s = 0.f;
    for (int b = 0; b < NB; ++b) {
        float mxv = -FLT_BIG, mnv = FLT_BIG;
        const float* pxr = pmax + ((size_t)b * 1024 + c) * 64;
        const float* pnr = pmin + ((size_t)b * 1024 + c) * 64;
        for (int q = 0; q < 64; ++q) {
            mxv = fmaxf(mxv, pxr[q]);
            mnv = fminf(mnv, pnr[q]);
        }
        const float v = (a >= 0.f) ? fmaf(a, mxv, sh) : fmaf(a, mnv, sh);
        h[b] = fmaxf(v, 0.f);
        s += h[b];
    }
    const float mean = s * (1.f / NB);
    float var = 0.f;
    for (int b = 0; b < NB; ++b) { const float d = h[b] - mean; var = fmaf(d, d, var); }
    var *= (1.f / NB);
    const double ai = (double)g4[c] / sqrt((double)var + 1e-5);
    for (int b = 0; b < NB; ++b)
        out[b * 1024 + c] = (float)(ai * ((double)h[b] - (double)mean) + (double)be4[c]);
}

extern "C" void kernel_launch(void* const* d_in, const int* in_sizes, int n_in,
                              void* d_out, int out_size, void* d_ws, size_t ws_size,
                              hipStream_t stream) {
    const float* xyz = (const float*)d_in[0];
    const float* W1  = (const float*)d_in[1];
    const float* b1  = (const float*)d_in[2];
    const float* g1  = (const float*)d_in[3];
    const float* be1 = (const float*)d_in[4];
    const float* W2  = (const float*)d_in[5];
    const float* b2  = (const float*)d_in[6];
    const float* g2  = (const float*)d_in[7];
    const float* be2 = (const float*)d_in[8];
    const float* W3  = (const float*)d_in[9];
    const float* b3  = (const float*)d_in[10];
    const float* g3  = (const float*)d_in[11];
    const float* be3 = (const float*)d_in[12];
    const float* g4  = (const float*)d_in[13];
    const float* be4 = (const float*)d_in[14];

    float* ws = (float*)d_ws;
    u16*   y1t = (u16*)(ws + OFF_Y1T);
    u16*   y2t = (u16*)(ws + OFF_Y2T);
    u16*   w1i = (u16*)(ws + OFF_W1I);
    u16*   w2i = (u16*)(ws + OFF_W2I);
    u16*   w3i = (u16*)(ws + OFF_W3I);
    float* ps  = ws + OFF_PS;
    float* pq  = ws + OFF_PQ;
    float* pmx = ws + OFF_PMX;
    float* pmn = ws + OFF_PMN;
    float2* ash = (float2*)(ws + OFF_ASH);
    float* out = (float*)d_out;

    // W images (2-plane): L1 128-chunks (42), L2 256-chunks (16), L3 256-chunks (64)
    prep_w<<<122, 256, 0, stream>>>(W1, W2, W3, w1i, w2i, w3i);

    // L1: 3-product fp32-B GEMM; writes pre-BN y1 2-plane tiles + stats
    gemm_L1<<<dim3(32, 2, 16), 256, 0, stream>>>(
        w1i, 21, 643, 256, b1, xyz, y1t, 8, ps, pq);
    stats_k<<<4, 256, 0, stream>>>(ps, pq, 256, g1, be1, ash);
    bnfix2<<<dim3(8, 32, 16), 256, 0, stream>>>(y1t, 8, ash);

    // L2: 3-product 2-half-phase GEMM on 2-plane y1; writes pre-BN y2 SINGLE-plane tiles
    gemm8p_L2<<<dim3(16, 2, 16), 512, 0, stream>>>(
        w2i, 8, 512, b2, y1t, y2t, 16, ps, pq, nullptr, nullptr);
    stats_k<<<8, 256, 0, stream>>>(ps, pq, 512, g2, be2, ash);
    bnfix1<<<dim3(16, 32, 16), 256, 0, stream>>>(y2t, 16, ash);

    // L3: 2-product 2-half-phase GEMM on 1-plane y2; stats + max/min partials (no y3)
    gemm8p_L3<<<dim3(16, 4, 16), 512, 0, stream>>>(
        w3i, 16, 1024, b3, y2t, nullptr, 0, ps, pq, pmx, pmn);

    // fused L3-stats + pool-select + final BN1d
    final_k<<<4, 256, 0, stream>>>(ps, pq, g3, be3, pmx, pmn, g4, be4, out);
}

// Round 25
// 444.773 us; speedup vs baseline: 1.2171x; 1.2171x over previous
//
#include <hip/hip_runtime.h>
#include <math.h>

typedef unsigned short u16;
typedef unsigned int   u32;
typedef __attribute__((ext_vector_type(8))) short short8;
typedef __attribute__((ext_vector_type(4))) float f32x4;

#define NPTS 4096
#define NB   16
#define FLT_BIG 3.402823466e38f

// ---- workspace layout (float offsets), total ~155 MB ----
static const size_t OFF_Y1T = 0;          // 33,554,432 u16 (64 MB) 2-plane
static const size_t OFF_Y2T = 16777216;   // 33,554,432 u16 (64 MB) 1-plane
static const size_t OFF_W1I = 33554432;   // 344064 u16
static const size_t OFF_W2I = 33726464;   // 262144 u16
static const size_t OFF_W3I = 33857536;   // 1048576 u16
static const size_t OFF_PS  = 34381824;
static const size_t OFF_PQ  = 35430400;
static const size_t OFF_PMX = 36478976;
static const size_t OFF_PMN = 37527552;
static const size_t OFF_ASH = 38576128;   // float2[1024]
static const size_t OFF_H   = 38578176;   // float[16*1024]

__device__ __forceinline__ void gload_lds16(const void* g, void* l) {
    __builtin_amdgcn_global_load_lds(
        (const __attribute__((address_space(1))) u32*)g,
        (__attribute__((address_space(3))) u32*)l, 16, 0, 0);
}
__device__ __forceinline__ u32 pk(u32 a, u32 b) {   // mem order [a.hi16, b.hi16]
    return __builtin_amdgcn_perm(b, a, 0x07060302u);
}
#define MFM(a, b, c) __builtin_amdgcn_mfma_f32_16x16x32_bf16(a, b, c, 0, 0, 0)

// ---- W prep (2-plane hi+mid): L1 128-chunks, L2/L3 256-chunks ----
__global__ __launch_bounds__(256) void prep_w(const float* __restrict__ W1,
                                              const float* __restrict__ W2,
                                              const float* __restrict__ W3,
                                              u16* __restrict__ w1i,
                                              u16* __restrict__ w2i,
                                              u16* __restrict__ w3i) {
    const int bx = blockIdx.x;
    if (bx < 42) {
        const int mc = bx / 21, kt = bx % 21;
        u16* tb = w1i + ((size_t)(mc * 21 + kt) << 13);
#pragma unroll
        for (int it = 0; it < 2; ++it) {
            const int item = it * 256 + threadIdx.x;
            const int m = item & 127, kot = item >> 7;
            const int k0 = kt * 32 + kot * 8;
            const float* wr = W1 + (size_t)(mc * 128 + m) * 643;
            u32 hh[8], mm[8];
#pragma unroll
            for (int j = 0; j < 8; ++j) {
                const int k = k0 + j;
                const float x = (k < 643) ? wr[k] : 0.f;
                const u32 u = __float_as_uint(x);
                const u32 uh = u + 0x8000u;
                const float r1 = x - __uint_as_float(uh & 0xFFFF0000u);
                hh[j] = uh;
                mm[j] = __float_as_uint(r1) + 0x8000u;
            }
            uint4 wh, wmv;
            wh.x = pk(hh[0], hh[1]); wh.y = pk(hh[2], hh[3]);
            wh.z = pk(hh[4], hh[5]); wh.w = pk(hh[6], hh[7]);
            wmv.x = pk(mm[0], mm[1]); wmv.y = pk(mm[2], mm[3]);
            wmv.z = pk(mm[4], mm[5]); wmv.w = pk(mm[6], mm[7]);
            u16* dst = tb + kot * 1024 + m * 8;
            *(uint4*)dst          = wh;
            *(uint4*)(dst + 4096) = wmv;
        }
    } else {
        const float* W; u16* img; int Kact, KT, mc, kt;
        if (bx < 58) { W = W2; img = w2i; Kact = 256; KT = 8;  const int t = bx - 42; mc = t >> 3; kt = t & 7; }
        else         { W = W3; img = w3i; Kact = 512; KT = 16; const int t = bx - 58; mc = t >> 4; kt = t & 15; }
        u16* tb = img + ((size_t)(mc * KT + kt) << 14);
#pragma unroll
        for (int it = 0; it < 4; ++it) {
            const int item = it * 256 + threadIdx.x;
            const int m = item & 255, kot = item >> 8;
            const int k0 = kt * 32 + kot * 8;
            const float* wr = W + (size_t)(mc * 256 + m) * Kact;
            u32 hh[8], mm[8];
#pragma unroll
            for (int j = 0; j < 8; ++j) {
                const int k = k0 + j;
                const float x = (k < Kact) ? wr[k] : 0.f;
                const u32 u = __float_as_uint(x);
                const u32 uh = u + 0x8000u;
                const float r1 = x - __uint_as_float(uh & 0xFFFF0000u);
                hh[j] = uh;
                mm[j] = __float_as_uint(r1) + 0x8000u;
            }
            uint4 wh, wmv;
            wh.x = pk(hh[0], hh[1]); wh.y = pk(hh[2], hh[3]);
            wh.z = pk(hh[4], hh[5]); wh.w = pk(hh[6], hh[7]);
            wmv.x = pk(mm[0], mm[1]); wmv.y = pk(mm[2], mm[3]);
            wmv.z = pk(mm[4], mm[5]); wmv.w = pk(mm[6], mm[7]);
            u16* dst = tb + kot * 2048 + m * 8;
            *(uint4*)dst          = wh;
            *(uint4*)(dst + 8192) = wmv;
        }
    }
}

// ---- bnfix2: in-place BN+ReLU on 2-plane tiles (y1) ----
__global__ __launch_bounds__(256) void bnfix2(u16* __restrict__ yt, int KT,
                                              const float2* __restrict__ ash) {
    const int kt = blockIdx.x, nt = blockIdx.y, b = blockIdx.z;
    u16* tb = yt + ((size_t)((b * 32 + nt) * KT + kt) << 13);
    const int n = threadIdx.x & 127, kh = threadIdx.x >> 7;
#pragma unroll
    for (int q = 0; q < 2; ++q) {
        const int kot = kh * 2 + q;
        u16* ph = tb + kot * 1024 + n * 8;
        uint4 H  = *(uint4*)ph;
        uint4 Mv = *(uint4*)(ph + 4096);
        u32 hw[4] = {H.x, H.y, H.z, H.w};
        u32 mw[4] = {Mv.x, Mv.y, Mv.z, Mv.w};
        u32 oh[4], om[4];
#pragma unroll
        for (int wi = 0; wi < 4; ++wi) {
            u32 uh2[2], um2[2];
#pragma unroll
            for (int e = 0; e < 2; ++e) {
                const u32 hb = e ? (hw[wi] & 0xFFFF0000u) : (hw[wi] << 16);
                const u32 mb = e ? (mw[wi] & 0xFFFF0000u) : (mw[wi] << 16);
                const float x = __uint_as_float(hb) + __uint_as_float(mb);
                const int k = kt * 32 + kot * 8 + wi * 2 + e;
                const float2 a = ash[k];
                const float y = fmaxf(fmaf(a.x, x, a.y), 0.f);
                const u32 uy = __float_as_uint(y) + 0x8000u;
                const float r1 = y - __uint_as_float(uy & 0xFFFF0000u);
                uh2[e] = uy;
                um2[e] = __float_as_uint(r1) + 0x8000u;
            }
            oh[wi] = pk(uh2[0], uh2[1]);
            om[wi] = pk(um2[0], um2[1]);
        }
        *(uint4*)ph          = make_uint4(oh[0], oh[1], oh[2], oh[3]);
        *(uint4*)(ph + 4096) = make_uint4(om[0], om[1], om[2], om[3]);
    }
}

// ---- bnfix1: in-place BN+ReLU on single-plane bf16 tiles (y2) ----
__global__ __launch_bounds__(256) void bnfix1(u16* __restrict__ yt, int KT,
                                              const float2* __restrict__ ash) {
    const int kt = blockIdx.x, nt = blockIdx.y, b = blockIdx.z;
    u16* tb = yt + ((size_t)((b * 32 + nt) * KT + kt) << 12);
    const int n = threadIdx.x & 127, kh = threadIdx.x >> 7;
#pragma unroll
    for (int q = 0; q < 2; ++q) {
        const int kot = kh * 2 + q;
        u16* ph = tb + kot * 1024 + n * 8;
        uint4 H = *(uint4*)ph;
        u32 hw[4] = {H.x, H.y, H.z, H.w};
        u32 oh[4];
#pragma unroll
        for (int wi = 0; wi < 4; ++wi) {
            u32 uh2[2];
#pragma unroll
            for (int e = 0; e < 2; ++e) {
                const u32 hb = e ? (hw[wi] & 0xFFFF0000u) : (hw[wi] << 16);
                const float x = __uint_as_float(hb);
                const int k = kt * 32 + kot * 8 + wi * 2 + e;
                const float2 a = ash[k];
                const float y = fmaxf(fmaf(a.x, x, a.y), 0.f);
                uh2[e] = __float_as_uint(y) + 0x8000u;
            }
            oh[wi] = pk(uh2[0], uh2[1]);
        }
        *(uint4*)ph = make_uint4(oh[0], oh[1], oh[2], oh[3]);
    }
}

// ================= L1 GEMM (fp32 B, 3-product, 128^2, dbuf; writes 2-plane y1) =================
__global__ __launch_bounds__(256)
void gemm_L1(const u16* __restrict__ Wimg, int KT, int Kact, int M_,
             const float* __restrict__ bias, const float* __restrict__ X,
             u16* __restrict__ Yt, int YKT,
             float* __restrict__ psum, float* __restrict__ psq)
{
    __shared__ __align__(16) u16 As_[2 * 8192];
    __shared__ __align__(16) u16 Bs_[2 * 8192];
    const int tid = threadIdx.x;
    const int lane = tid & 63, wid = tid >> 6;
    const int l15 = lane & 15, l4 = lane >> 4;
    const int wm = wid >> 1, wn = wid & 1;
    const int nt = blockIdx.x, mtb = blockIdx.y, b = blockIdx.z;
    const int m0 = mtb * 128, n0 = nt * 128;
    const int nb = tid & 127, kh = tid >> 7;
    f32x4 acc[4][4];
#pragma unroll
    for (int i = 0; i < 4; ++i)
#pragma unroll
        for (int j = 0; j < 4; ++j) acc[i][j] = (f32x4){0.f, 0.f, 0.f, 0.f};
    const u16* wtile = Wimg + ((size_t)mtb * KT << 13);
    const int afo = l4 * 1024 + (wm * 64 + l15) * 8;
    const int bfo = l4 * 1024 + (wn * 64 + l15) * 8;
    float xr[16];

#define L1_STAGE_A(kt, buf)                                                       \
    {                                                                             \
        const u16* g_ = wtile + ((size_t)(kt) << 13);                             \
        u16* l_ = As_ + ((buf) << 13);                                            \
        _Pragma("unroll")                                                         \
        for (int i_ = 0; i_ < 4; ++i_)                                            \
            gload_lds16(g_ + (wid * 4 + i_) * 512 + lane * 8,                     \
                        l_ + (wid * 4 + i_) * 512);                               \
    }
#define L1_READ_B(kt)                                                             \
    {                                                                             \
        const int kb_ = (kt) * 32 + kh * 16;                                      \
        const float* src_ = X + ((size_t)b * Kact + kb_) * NPTS + n0 + nb;        \
        _Pragma("unroll")                                                         \
        for (int j_ = 0; j_ < 16; ++j_)                                           \
            xr[j_] = (kb_ + j_ < Kact) ? src_[(size_t)j_ * NPTS] : 0.f;           \
    }
#define L1_WRITE_B(buf)                                                           \
    {                                                                             \
        u32 hh_[16], mm_[16];                                                     \
        _Pragma("unroll")                                                         \
        for (int j_ = 0; j_ < 16; ++j_) {                                         \
            const float x_ = xr[j_];                                              \
            const u32 u_ = __float_as_uint(x_);                                   \
            const u32 uh_ = u_ + 0x8000u;                                         \
            const float r1_ = x_ - __uint_as_float(uh_ & 0xFFFF0000u);            \
            hh_[j_] = uh_;                                                        \
            mm_[j_] = __float_as_uint(r1_) + 0x8000u;                             \
        }                                                                         \
        u16* bb_ = Bs_ + ((buf) << 13);                                           \
        _Pragma("unroll")                                                         \
        for (int q_ = 0; q_ < 2; ++q_) {                                          \
            uint4 wh_, wm_;                                                       \
            wh_.x = pk(hh_[q_*8+0], hh_[q_*8+1]); wh_.y = pk(hh_[q_*8+2], hh_[q_*8+3]); \
            wh_.z = pk(hh_[q_*8+4], hh_[q_*8+5]); wh_.w = pk(hh_[q_*8+6], hh_[q_*8+7]); \
            wm_.x = pk(mm_[q_*8+0], mm_[q_*8+1]); wm_.y = pk(mm_[q_*8+2], mm_[q_*8+3]); \
            wm_.z = pk(mm_[q_*8+4], mm_[q_*8+5]); wm_.w = pk(mm_[q_*8+6], mm_[q_*8+7]); \
            const int kot_ = kh * 2 + q_;                                         \
            *(uint4*)(bb_ + kot_ * 1024 + nb * 8)        = wh_;                   \
            *(uint4*)(bb_ + 4096 + kot_ * 1024 + nb * 8) = wm_;                   \
        }                                                                         \
    }
#define L1_COMPUTE(buf)                                                           \
    {                                                                             \
        const u16* A_ = As_ + ((buf) << 13);                                      \
        const u16* B_ = Bs_ + ((buf) << 13);                                      \
        short8 ah_[4], am_[4];                                                    \
        _Pragma("unroll")                                                         \
        for (int mf_ = 0; mf_ < 4; ++mf_) {                                       \
            ah_[mf_] = *(const short8*)(A_ + afo + mf_ * 128);                    \
            am_[mf_] = *(const short8*)(A_ + 4096 + afo + mf_ * 128);             \
        }                                                                         \
        _Pragma("unroll")                                                         \
        for (int nf_ = 0; nf_ < 4; ++nf_) {                                       \
            const short8 bh_ = *(const short8*)(B_ + bfo + nf_ * 128);            \
            const short8 bm_ = *(const short8*)(B_ + 4096 + bfo + nf_ * 128);     \
            _Pragma("unroll")                                                     \
            for (int mf_ = 0; mf_ < 4; ++mf_)                                     \
                acc[mf_][nf_] = MFM(ah_[mf_], bh_, acc[mf_][nf_]);                \
            _Pragma("unroll")                                                     \
            for (int mf_ = 0; mf_ < 4; ++mf_)                                     \
                acc[mf_][nf_] = MFM(ah_[mf_], bm_, acc[mf_][nf_]);                \
            _Pragma("unroll")                                                     \
            for (int mf_ = 0; mf_ < 4; ++mf_)                                     \
                acc[mf_][nf_] = MFM(am_[mf_], bh_, acc[mf_][nf_]);                \
        }                                                                         \
    }

    int o = 0;
    L1_READ_B(0);
    L1_STAGE_A(0, 0);
    L1_WRITE_B(0);
    __syncthreads();
    for (int kt = 0; kt < KT; ++kt) {
        if (kt + 1 < KT) {
            L1_READ_B(kt + 1);
            L1_STAGE_A(kt + 1, o ^ 1);
        }
        L1_COMPUTE(o);
        if (kt + 1 < KT) { L1_WRITE_B(o ^ 1); }
        __syncthreads();
        o ^= 1;
    }

    u16* ytb = Yt + ((size_t)((b * 32 + nt) * YKT) << 13);
#pragma unroll
    for (int mf = 0; mf < 4; ++mf) {
        const int kb = m0 + wm * 64 + mf * 16 + l4 * 4;
        float v4[4][4];
#pragma unroll
        for (int r = 0; r < 4; ++r) {
            const int m = kb + r;
            const float bvv = bias[m];
            float rs = 0.f, rq = 0.f;
#pragma unroll
            for (int nf = 0; nf < 4; ++nf) {
                const float v = acc[mf][nf][r] + bvv;
                v4[r][nf] = v; rs += v; rq = fmaf(v, v, rq);
            }
#pragma unroll
            for (int s = 1; s < 16; s <<= 1) {
                rs += __shfl_xor(rs, s);
                rq += __shfl_xor(rq, s);
            }
            if (l15 == 0) {
                const int slot = (b * 32 + nt) * 2 + wn;
                psum[(size_t)slot * M_ + m] = rs;
                psq[(size_t)slot * M_ + m]  = rq;
            }
        }
        {
            const int ktp = kb >> 5, kot = (kb >> 3) & 3, j0 = kb & 7;
            u16* dt = ytb + ((size_t)ktp << 13) + kot * 1024 + j0;
#pragma unroll
            for (int nf = 0; nf < 4; ++nf) {
                const int nwi = wn * 64 + nf * 16 + l15;
                u32 uh[4], um[4];
#pragma unroll
                for (int r = 0; r < 4; ++r) {
                    const float v = v4[r][nf];
                    const u32 a = __float_as_uint(v) + 0x8000u;
                    const float r1 = v - __uint_as_float(a & 0xFFFF0000u);
                    uh[r] = a;
                    um[r] = __float_as_uint(r1) + 0x8000u;
                }
                uint2 wh2; wh2.x = pk(uh[0], uh[1]); wh2.y = pk(uh[2], uh[3]);
                uint2 wm2; wm2.x = pk(um[0], um[1]); wm2.y = pk(um[2], um[3]);
                *(uint2*)(dt + nwi * 8)        = wh2;
                *(uint2*)(dt + 4096 + nwi * 8) = wm2;
            }
        }
    }
}

// ================= 8-phase 256^2 kernels =================
#define G8_PARAMS                                                                 \
    const u16* __restrict__ Wimg, int KT, int M_,                                 \
    const float* __restrict__ bias,                                               \
    const u16* __restrict__ Bt,                                                   \
    u16* __restrict__ Yt, int YKT,                                                \
    float* __restrict__ psum, float* __restrict__ psq,                            \
    float* __restrict__ pmax, float* __restrict__ pmin

#define STAGE_A8(kt, buf)                                                         \
    {                                                                             \
        const u16* g_ = wtile + ((size_t)(kt) << 14);                             \
        u16* l_ = As_ + ((buf) << 14);                                            \
        _Pragma("unroll")                                                         \
        for (int i_ = 0; i_ < 4; ++i_)                                            \
            gload_lds16(g_ + (wid * 4 + i_) * 512 + lane * 8,                     \
                        l_ + (wid * 4 + i_) * 512);                               \
    }
#define STAGE_B8_3P(kt, buf)                                                      \
    {                                                                             \
        const u16* g_ = btw + ((size_t)(kt) << 13);                               \
        u16* l_ = Bs_ + ((buf) << 14) + (wm << 13);                               \
        _Pragma("unroll")                                                         \
        for (int i_ = 0; i_ < 4; ++i_)                                            \
            gload_lds16(g_ + (wn * 4 + i_) * 512 + lane * 8,                      \
                        l_ + (wn * 4 + i_) * 512);                                \
    }
#define STAGE_B8_2P(kt, buf)                                                      \
    {                                                                             \
        const u16* g_ = btw + ((size_t)(kt) << 12);                               \
        u16* l_ = Bs_ + ((buf) << 13) + (wm << 12);                               \
        _Pragma("unroll")                                                         \
        for (int i_ = 0; i_ < 2; ++i_)                                            \
            gload_lds16(g_ + (wn * 2 + i_) * 512 + lane * 8,                      \
                        l_ + (wn * 2 + i_) * 512);                                \
    }

#define MFMA_BLK(q, a0, a1, B0, B1, B2, B3)                                       \
        acc[2*(q)][0]   = MFM(a0, B0, acc[2*(q)][0]);                             \
        acc[2*(q)+1][0] = MFM(a1, B0, acc[2*(q)+1][0]);                           \
        acc[2*(q)][1]   = MFM(a0, B1, acc[2*(q)][1]);                             \
        acc[2*(q)+1][1] = MFM(a1, B1, acc[2*(q)+1][1]);                           \
        acc[2*(q)][2]   = MFM(a0, B2, acc[2*(q)][2]);                             \
        acc[2*(q)+1][2] = MFM(a1, B2, acc[2*(q)+1][2]);                           \
        acc[2*(q)][3]   = MFM(a0, B3, acc[2*(q)][3]);                             \
        acc[2*(q)+1][3] = MFM(a1, B3, acc[2*(q)+1][3]);

// ---- L2: 2 half-phases/kt, 48 MFMA/phase (3-product). Stage A+B at p0; vmcnt at p1. ----
#define PHASE2_3P(p, CUR, NXT, kt)                                                \
    {                                                                             \
        const u16* A_ = As_ + ((CUR) << 14);                                      \
        short8 a0h = *(const short8*)(A_ + aof + (4 * (p) + 0) * 128);            \
        short8 a1h = *(const short8*)(A_ + aof + (4 * (p) + 1) * 128);            \
        short8 a2h = *(const short8*)(A_ + aof + (4 * (p) + 2) * 128);            \
        short8 a3h = *(const short8*)(A_ + aof + (4 * (p) + 3) * 128);            \
        short8 a0m = *(const short8*)(A_ + 8192 + aof + (4 * (p) + 0) * 128);     \
        short8 a1m = *(const short8*)(A_ + 8192 + aof + (4 * (p) + 1) * 128);     \
        short8 a2m = *(const short8*)(A_ + 8192 + aof + (4 * (p) + 2) * 128);     \
        short8 a3m = *(const short8*)(A_ + 8192 + aof + (4 * (p) + 3) * 128);     \
        if ((p) == 0) {                                                           \
            const u16* B_ = Bs_ + ((CUR) << 14) + bof;                            \
            bh0 = *(const short8*)(B_);                                           \
            bh1 = *(const short8*)(B_ + 128);                                     \
            bh2 = *(const short8*)(B_ + 256);                                     \
            bh3 = *(const short8*)(B_ + 384);                                     \
            bm0 = *(const short8*)(B_ + 4096);                                    \
            bm1 = *(const short8*)(B_ + 4096 + 128);                              \
            bm2 = *(const short8*)(B_ + 4096 + 256);                              \
            bm3 = *(const short8*)(B_ + 4096 + 384);                              \
        }                                                                         \
        if ((p) == 0 && (kt) + 1 < KT) {                                          \
            STAGE_A8((kt) + 1, NXT);                                              \
            STAGE_B8_3P((kt) + 1, NXT);                                           \
        }                                                                         \
        if ((p) == 1) { asm volatile("s_waitcnt vmcnt(0)" ::: "memory"); }        \
        __builtin_amdgcn_sched_barrier(0);                                        \
        __builtin_amdgcn_s_barrier();                                             \
        asm volatile("s_waitcnt lgkmcnt(0)" ::: "memory");                        \
        __builtin_amdgcn_sched_barrier(0);                                        \
        __builtin_amdgcn_s_setprio(1);                                            \
        MFMA_BLK(2*(p),     a0h, a1h, bh0, bh1, bh2, bh3)                         \
        MFMA_BLK(2*(p) + 1, a2h, a3h, bh0, bh1, bh2, bh3)                         \
        MFMA_BLK(2*(p),     a0h, a1h, bm0, bm1, bm2, bm3)                         \
        MFMA_BLK(2*(p) + 1, a2h, a3h, bm0, bm1, bm2, bm3)                         \
        MFMA_BLK(2*(p),     a0m, a1m, bh0, bh1, bh2, bh3)                         \
        MFMA_BLK(2*(p) + 1, a2m, a3m, bh0, bh1, bh2, bh3)                         \
        __builtin_amdgcn_s_setprio(0);                                            \
    }

// ---- L3: 2 half-phases/kt, 32 MFMA/phase (2-product). Stage A+B at p0; vmcnt at p1. ----
#define PHASE2_2P(p, CUR, NXT, kt)                                                \
    {                                                                             \
        const u16* A_ = As_ + ((CUR) << 14);                                      \
        short8 a0h = *(const short8*)(A_ + aof + (4 * (p) + 0) * 128);            \
        short8 a1h = *(const short8*)(A_ + aof + (4 * (p) + 1) * 128);            \
        short8 a2h = *(const short8*)(A_ + aof + (4 * (p) + 2) * 128);            \
        short8 a3h = *(const short8*)(A_ + aof + (4 * (p) + 3) * 128);            \
        short8 a0m = *(const short8*)(A_ + 8192 + aof + (4 * (p) + 0) * 128);     \
        short8 a1m = *(const short8*)(A_ + 8192 + aof + (4 * (p) + 1) * 128);     \
        short8 a2m = *(const short8*)(A_ + 8192 + aof + (4 * (p) + 2) * 128);     \
        short8 a3m = *(const short8*)(A_ + 8192 + aof + (4 * (p) + 3) * 128);     \
        if ((p) == 0) {                                                           \
            const u16* B_ = Bs_ + ((CUR) << 13) + bof;                            \
            bh0 = *(const short8*)(B_);                                           \
            bh1 = *(const short8*)(B_ + 128);                                     \
            bh2 = *(const short8*)(B_ + 256);                                     \
            bh3 = *(const short8*)(B_ + 384);                                     \
        }                                                                         \
        if ((p) == 0 && (kt) + 1 < KT) {                                          \
            STAGE_A8((kt) + 1, NXT);                                              \
            STAGE_B8_2P((kt) + 1, NXT);                                           \
        }                                                                         \
        if ((p) == 1) { asm volatile("s_waitcnt vmcnt(0)" ::: "memory"); }        \
        __builtin_amdgcn_sched_barrier(0);                                        \
        __builtin_amdgcn_s_barrier();                                             \
        asm volatile("s_waitcnt lgkmcnt(0)" ::: "memory");                        \
        __builtin_amdgcn_sched_barrier(0);                                        \
        __builtin_amdgcn_s_setprio(1);                                            \
        MFMA_BLK(2*(p),     a0h, a1h, bh0, bh1, bh2, bh3)                         \
        MFMA_BLK(2*(p) + 1, a2h, a3h, bh0, bh1, bh2, bh3)                         \
        MFMA_BLK(2*(p),     a0m, a1m, bh0, bh1, bh2, bh3)                         \
        MFMA_BLK(2*(p) + 1, a2m, a3m, bh0, bh1, bh2, bh3)                         \
        __builtin_amdgcn_s_setprio(0);                                            \
    }

#define G8_EPILOGUE(STOREP, MAXMIN)                                               \
    _Pragma("unroll")                                                             \
    for (int mf = 0; mf < 8; ++mf) {                                              \
        const int mbase = mtb * 256 + wm * 128 + mf * 16 + l4 * 4;                \
        float v4[4][4];                                                           \
        _Pragma("unroll")                                                         \
        for (int r = 0; r < 4; ++r) {                                             \
            const int m = mbase + r;                                              \
            const float bvv = bias[m];                                            \
            float rs = 0.f, rq = 0.f;                                             \
            _Pragma("unroll")                                                     \
            for (int nf = 0; nf < 4; ++nf) {                                      \
                const float v = acc[mf][nf][r] + bvv;                             \
                v4[r][nf] = v; rs += v; rq = fmaf(v, v, rq);                      \
            }                                                                     \
            float mx = 0.f, mn = 0.f;                                             \
            if (MAXMIN) {                                                         \
                mx = fmaxf(fmaxf(v4[r][0], v4[r][1]), fmaxf(v4[r][2], v4[r][3])); \
                mn = fminf(fminf(v4[r][0], v4[r][1]), fminf(v4[r][2], v4[r][3])); \
            }                                                                     \
            _Pragma("unroll")                                                     \
            for (int s = 1; s < 16; s <<= 1) {                                    \
                rs += __shfl_xor(rs, s);                                          \
                rq += __shfl_xor(rq, s);                                          \
                if (MAXMIN) {                                                     \
                    mx = fmaxf(mx, __shfl_xor(mx, s));                            \
                    mn = fminf(mn, __shfl_xor(mn, s));                            \
                }                                                                 \
            }                                                                     \
            if (l15 == 0) {                                                       \
                const int slot = (b * 16 + ntb) * 4 + wn;                         \
                psum[(size_t)slot * M_ + m] = rs;                                 \
                psq[(size_t)slot * M_ + m]  = rq;                                 \
                if (MAXMIN) {                                                     \
                    pmax[((size_t)b * M_ + m) * 64 + ntb * 4 + wn] = mx;          \
                    pmin[((size_t)b * M_ + m) * 64 + ntb * 4 + wn] = mn;          \
                }                                                                 \
            }                                                                     \
        }                                                                         \
        if (STOREP) {                                                             \
            const int ktp = mbase >> 5, kot = (mbase >> 3) & 3, j0 = mbase & 7;   \
            u16* dt = ytb + ((size_t)ktp << 12) + kot * 1024 + j0;                \
            _Pragma("unroll")                                                     \
            for (int nf = 0; nf < 4; ++nf) {                                      \
                const int nwi = (wn & 1) * 64 + nf * 16 + l15;                    \
                u32 uh[4];                                                        \
                _Pragma("unroll")                                                 \
                for (int r = 0; r < 4; ++r)                                       \
                    uh[r] = __float_as_uint(v4[r][nf]) + 0x8000u;                 \
                uint2 wh2; wh2.x = pk(uh[0], uh[1]); wh2.y = pk(uh[2], uh[3]);    \
                *(uint2*)(dt + nwi * 8) = wh2;                                    \
            }                                                                     \
        }                                                                         \
    }

// L2: 3-product, 2-plane B (y1); 2 half-phases/kt; stores y2 single-plane
__global__ __launch_bounds__(512) void gemm8p_L2(G8_PARAMS)
{
    __shared__ __align__(16) u16 As_[2 * 16384];
    __shared__ __align__(16) u16 Bs_[2 * 16384];
    const int tid = threadIdx.x;
    const int lane = tid & 63, wid = tid >> 6;
    const int l15 = lane & 15, l4 = lane >> 4;
    const int wm = wid >> 2, wn = wid & 3;
    const int ntb = blockIdx.x, mtb = blockIdx.y, b = blockIdx.z;
    f32x4 acc[8][4];
#pragma unroll
    for (int i = 0; i < 8; ++i)
#pragma unroll
        for (int j = 0; j < 4; ++j) acc[i][j] = (f32x4){0.f, 0.f, 0.f, 0.f};
    const u16* wtile = Wimg + ((size_t)(mtb * KT) << 14);
    const u16* btw = Bt + ((size_t)((b * 32 + ntb * 2 + wm) * KT) << 13);
    const int aof = l4 * 2048 + (wm * 128 + l15) * 8;
    const int bof = (wn >> 1) * 8192 + l4 * 1024 + ((wn & 1) * 64 + l15) * 8;
    short8 bh0, bh1, bh2, bh3, bm0, bm1, bm2, bm3;
    STAGE_A8(0, 0)
    STAGE_B8_3P(0, 0)
    asm volatile("s_waitcnt vmcnt(0)" ::: "memory");
    __builtin_amdgcn_s_barrier();
    for (int kt = 0; kt < KT; kt += 2) {
        PHASE2_3P(0, 0, 1, kt) PHASE2_3P(1, 0, 1, kt)
        PHASE2_3P(0, 1, 0, kt + 1) PHASE2_3P(1, 1, 0, kt + 1)
    }
    u16* ytb = Yt + ((size_t)((b * 32 + ntb * 2 + (wn >> 1)) * YKT) << 12);
    G8_EPILOGUE(true, false)
}

// L3: 2-product, 1-plane B (y2); 2 half-phases/kt; max/min partials, no store
__global__ __launch_bounds__(512) void gemm8p_L3(G8_PARAMS)
{
    __shared__ __align__(16) u16 As_[2 * 16384];
    __shared__ __align__(16) u16 Bs_[2 * 8192];
    const int tid = threadIdx.x;
    const int lane = tid & 63, wid = tid >> 6;
    const int l15 = lane & 15, l4 = lane >> 4;
    const int wm = wid >> 2, wn = wid & 3;
    const int ntb = blockIdx.x, mtb = blockIdx.y, b = blockIdx.z;
    f32x4 acc[8][4];
#pragma unroll
    for (int i = 0; i < 8; ++i)
#pragma unroll
        for (int j = 0; j < 4; ++j) acc[i][j] = (f32x4){0.f, 0.f, 0.f, 0.f};
    const u16* wtile = Wimg + ((size_t)(mtb * KT) << 14);
    const u16* btw = Bt + ((size_t)((b * 32 + ntb * 2 + wm) * KT) << 12);
    const int aof = l4 * 2048 + (wm * 128 + l15) * 8;
    const int bof = (wn >> 1) * 4096 + l4 * 1024 + ((wn & 1) * 64 + l15) * 8;
    short8 bh0, bh1, bh2, bh3;
    STAGE_A8(0, 0)
    STAGE_B8_2P(0, 0)
    asm volatile("s_waitcnt vmcnt(0)" ::: "memory");
    __builtin_amdgcn_s_barrier();
    for (int kt = 0; kt < KT; kt += 2) {
        PHASE2_2P(0, 0, 1, kt) PHASE2_2P(1, 0, 1, kt)
        PHASE2_2P(0, 1, 0, kt + 1) PHASE2_2P(1, 1, 0, kt + 1)
    }
    u16* ytb = nullptr;
    G8_EPILOGUE(false, true)
}

// ---- per-channel stats (1024 slots) -> BN scale/shift ----
__global__ __launch_bounds__(256) void stats_k(const float* __restrict__ psum, const float* __restrict__ psq,
                                               int M_,
                                               const float* __restrict__ g, const float* __restrict__ be,
                                               float2* __restrict__ ash)
{
    __shared__ double ds[4][64];
    __shared__ double dq[4][64];
    const int mloc = threadIdx.x & 63, q = threadIdx.x >> 6;
    const int m = blockIdx.x * 64 + mloc;
    double s = 0.0, sq = 0.0;
    for (int sl = q * 256; sl < (q + 1) * 256; ++sl) {
        s  += (double)psum[(size_t)sl * M_ + m];
        sq += (double)psq[(size_t)sl * M_ + m];
    }
    ds[q][mloc] = s; dq[q][mloc] = sq;
    __syncthreads();
    if (threadIdx.x < 64) {
        const double S = ds[0][mloc] + ds[1][mloc] + ds[2][mloc] + ds[3][mloc];
        const double Q = dq[0][mloc] + dq[1][mloc] + dq[2][mloc] + dq[3][mloc];
        const double cnt = (double)NB * (double)NPTS;
        double mean = S / cnt;
        double var  = Q / cnt - mean * mean;
        if (var < 0.0) var = 0.0;
        const double a = (double)g[m] / sqrt(var + 1e-5);
        ash[m] = make_float2((float)a, (float)((double)be[m] - a * mean));
    }
}

// ---- pool_k: per-(b,c) max/min select + BN-apply + ReLU -> h[b*1024+c] ----
__global__ __launch_bounds__(256) void pool_k(const float2* __restrict__ ash3,
                                              const float* __restrict__ pmax,
                                              const float* __restrict__ pmin,
                                              float* __restrict__ h)
{
    const int c = blockIdx.x * 256 + threadIdx.x;   // grid.x = 4
    const int b = blockIdx.y;                       // grid.y = 16
    const float2 a = ash3[c];
    const float* pxr = pmax + ((size_t)b * 1024 + c) * 64;
    const float* pnr = pmin + ((size_t)b * 1024 + c) * 64;
    float mxv = -FLT_BIG, mnv = FLT_BIG;
    for (int q = 0; q < 64; ++q) {
        mxv = fmaxf(mxv, pxr[q]);
        mnv = fminf(mnv, pnr[q]);
    }
    const float v = (a.x >= 0.f) ? fmaf(a.x, mxv, a.y) : fmaf(a.x, mnv, a.y);
    h[b * 1024 + c] = fmaxf(v, 0.f);
}

// ---- bn1d_k: final BN1d over batch (identical numerics to old final_k tail) ----
__global__ __launch_bounds__(256) void bn1d_k(const float* __restrict__ h,
                                              const float* __restrict__ g4,
                                              const float* __restrict__ be4,
                                              float* __restrict__ out)
{
    const int c = blockIdx.x * 256 + threadIdx.x;
    if (c >= 1024) return;
    float hv[NB];
    float s = 0.f;
    for (int b = 0; b < NB; ++b) {
        hv[b] = h[b * 1024 + c];
        s += hv[b];
    }
    const float mean = s * (1.f / NB);
    float var = 0.f;
    for (int b = 0; b < NB; ++b) { const float d = hv[b] - mean; var = fmaf(d, d, var); }
    var *= (1.f / NB);
    const double ai = (double)g4[c] / sqrt((double)var + 1e-5);
    for (int b = 0; b < NB; ++b)
        out[b * 1024 + c] = (float)(ai * ((double)hv[b] - (double)mean) + (double)be4[c]);
}

extern "C" void kernel_launch(void* const* d_in, const int* in_sizes, int n_in,
                              void* d_out, int out_size, void* d_ws, size_t ws_size,
                              hipStream_t stream) {
    const float* xyz = (const float*)d_in[0];
    const float* W1  = (const float*)d_in[1];
    const float* b1  = (const float*)d_in[2];
    const float* g1  = (const float*)d_in[3];
    const float* be1 = (const float*)d_in[4];
    const float* W2  = (const float*)d_in[5];
    const float* b2  = (const float*)d_in[6];
    const float* g2  = (const float*)d_in[7];
    const float* be2 = (const float*)d_in[8];
    const float* W3  = (const float*)d_in[9];
    const float* b3  = (const float*)d_in[10];
    const float* g3  = (const float*)d_in[11];
    const float* be3 = (const float*)d_in[12];
    const float* g4  = (const float*)d_in[13];
    const float* be4 = (const float*)d_in[14];

    float* ws = (float*)d_ws;
    u16*   y1t = (u16*)(ws + OFF_Y1T);
    u16*   y2t = (u16*)(ws + OFF_Y2T);
    u16*   w1i = (u16*)(ws + OFF_W1I);
    u16*   w2i = (u16*)(ws + OFF_W2I);
    u16*   w3i = (u16*)(ws + OFF_W3I);
    float* ps  = ws + OFF_PS;
    float* pq  = ws + OFF_PQ;
    float* pmx = ws + OFF_PMX;
    float* pmn = ws + OFF_PMN;
    float2* ash = (float2*)(ws + OFF_ASH);
    float* h   = ws + OFF_H;
    float* out = (float*)d_out;

    // W images (2-plane): L1 128-chunks (42), L2 256-chunks (16), L3 256-chunks (64)
    prep_w<<<122, 256, 0, stream>>>(W1, W2, W3, w1i, w2i, w3i);

    // L1: 3-product fp32-B GEMM; writes pre-BN y1 2-plane tiles + stats
    gemm_L1<<<dim3(32, 2, 16), 256, 0, stream>>>(
        w1i, 21, 643, 256, b1, xyz, y1t, 8, ps, pq);
    stats_k<<<4, 256, 0, stream>>>(ps, pq, 256, g1, be1, ash);
    bnfix2<<<dim3(8, 32, 16), 256, 0, stream>>>(y1t, 8, ash);

    // L2: 3-product 2-half-phase GEMM on 2-plane y1; writes pre-BN y2 SINGLE-plane tiles
    gemm8p_L2<<<dim3(16, 2, 16), 512, 0, stream>>>(
        w2i, 8, 512, b2, y1t, y2t, 16, ps, pq, nullptr, nullptr);
    stats_k<<<8, 256, 0, stream>>>(ps, pq, 512, g2, be2, ash);
    bnfix1<<<dim3(16, 32, 16), 256, 0, stream>>>(y2t, 16, ash);

    // L3: 2-product 2-half-phase GEMM on 1-plane y2; stats + max/min partials (no y3)
    gemm8p_L3<<<dim3(16, 4, 16), 512, 0, stream>>>(
        w3i, 16, 1024, b3, y2t, nullptr, 0, ps, pq, pmx, pmn);

    // parallelized tail: L3 channel stats (16 blocks) -> pool (64 blocks) -> BN1d
    stats_k<<<16, 256, 0, stream>>>(ps, pq, 1024, g3, be3, ash);
    pool_k<<<dim3(4, 16), 256, 0, stream>>>(ash, pmx, pmn, h);
    bn1d_k<<<4, 256, 0, stream>>>(h, g4, be4, out);
}

// Round 26
// 403.235 us; speedup vs baseline: 1.3425x; 1.1030x over previous
//
#include <hip/hip_runtime.h>
#include <math.h>

typedef unsigned short u16;
typedef unsigned int   u32;
typedef __attribute__((ext_vector_type(8))) short short8;
typedef __attribute__((ext_vector_type(4))) float f32x4;

#define NPTS 4096
#define NB   16
#define FLT_BIG 3.402823466e38f

// ---- workspace layout (float offsets), total ~155 MB ----
static const size_t OFF_Y1T = 0;          // 33,554,432 u16 (64 MB) 2-plane
static const size_t OFF_Y2T = 16777216;   // 33,554,432 u16 (64 MB) 1-plane
static const size_t OFF_W1I = 33554432;   // 344064 u16
static const size_t OFF_W2I = 33726464;   // 262144 u16
static const size_t OFF_W3I = 33857536;   // 1048576 u16
static const size_t OFF_PS  = 34381824;
static const size_t OFF_PQ  = 35430400;
static const size_t OFF_PMX = 36478976;
static const size_t OFF_PMN = 37527552;
static const size_t OFF_ASH = 38576128;   // float2[1024]
static const size_t OFF_H   = 38578176;   // float[16*1024]
static const size_t OFF_DPS = 38594560;   // double[16*1024] (32768 floats)
static const size_t OFF_DPQ = 38627328;   // double[16*1024]

__device__ __forceinline__ void gload_lds16(const void* g, void* l) {
    __builtin_amdgcn_global_load_lds(
        (const __attribute__((address_space(1))) u32*)g,
        (__attribute__((address_space(3))) u32*)l, 16, 0, 0);
}
__device__ __forceinline__ u32 pk(u32 a, u32 b) {   // mem order [a.hi16, b.hi16]
    return __builtin_amdgcn_perm(b, a, 0x07060302u);
}
#define MFM(a, b, c) __builtin_amdgcn_mfma_f32_16x16x32_bf16(a, b, c, 0, 0, 0)

// ---- W prep (2-plane hi+mid): L1 128-chunks, L2/L3 256-chunks ----
__global__ __launch_bounds__(256) void prep_w(const float* __restrict__ W1,
                                              const float* __restrict__ W2,
                                              const float* __restrict__ W3,
                                              u16* __restrict__ w1i,
                                              u16* __restrict__ w2i,
                                              u16* __restrict__ w3i) {
    const int bx = blockIdx.x;
    if (bx < 42) {
        const int mc = bx / 21, kt = bx % 21;
        u16* tb = w1i + ((size_t)(mc * 21 + kt) << 13);
#pragma unroll
        for (int it = 0; it < 2; ++it) {
            const int item = it * 256 + threadIdx.x;
            const int m = item & 127, kot = item >> 7;
            const int k0 = kt * 32 + kot * 8;
            const float* wr = W1 + (size_t)(mc * 128 + m) * 643;
            u32 hh[8], mm[8];
#pragma unroll
            for (int j = 0; j < 8; ++j) {
                const int k = k0 + j;
                const float x = (k < 643) ? wr[k] : 0.f;
                const u32 u = __float_as_uint(x);
                const u32 uh = u + 0x8000u;
                const float r1 = x - __uint_as_float(uh & 0xFFFF0000u);
                hh[j] = uh;
                mm[j] = __float_as_uint(r1) + 0x8000u;
            }
            uint4 wh, wmv;
            wh.x = pk(hh[0], hh[1]); wh.y = pk(hh[2], hh[3]);
            wh.z = pk(hh[4], hh[5]); wh.w = pk(hh[6], hh[7]);
            wmv.x = pk(mm[0], mm[1]); wmv.y = pk(mm[2], mm[3]);
            wmv.z = pk(mm[4], mm[5]); wmv.w = pk(mm[6], mm[7]);
            u16* dst = tb + kot * 1024 + m * 8;
            *(uint4*)dst          = wh;
            *(uint4*)(dst + 4096) = wmv;
        }
    } else {
        const float* W; u16* img; int Kact, KT, mc, kt;
        if (bx < 58) { W = W2; img = w2i; Kact = 256; KT = 8;  const int t = bx - 42; mc = t >> 3; kt = t & 7; }
        else         { W = W3; img = w3i; Kact = 512; KT = 16; const int t = bx - 58; mc = t >> 4; kt = t & 15; }
        u16* tb = img + ((size_t)(mc * KT + kt) << 14);
#pragma unroll
        for (int it = 0; it < 4; ++it) {
            const int item = it * 256 + threadIdx.x;
            const int m = item & 255, kot = item >> 8;
            const int k0 = kt * 32 + kot * 8;
            const float* wr = W + (size_t)(mc * 256 + m) * Kact;
            u32 hh[8], mm[8];
#pragma unroll
            for (int j = 0; j < 8; ++j) {
                const int k = k0 + j;
                const float x = (k < Kact) ? wr[k] : 0.f;
                const u32 u = __float_as_uint(x);
                const u32 uh = u + 0x8000u;
                const float r1 = x - __uint_as_float(uh & 0xFFFF0000u);
                hh[j] = uh;
                mm[j] = __float_as_uint(r1) + 0x8000u;
            }
            uint4 wh, wmv;
            wh.x = pk(hh[0], hh[1]); wh.y = pk(hh[2], hh[3]);
            wh.z = pk(hh[4], hh[5]); wh.w = pk(hh[6], hh[7]);
            wmv.x = pk(mm[0], mm[1]); wmv.y = pk(mm[2], mm[3]);
            wmv.z = pk(mm[4], mm[5]); wmv.w = pk(mm[6], mm[7]);
            u16* dst = tb + kot * 2048 + m * 8;
            *(uint4*)dst          = wh;
            *(uint4*)(dst + 8192) = wmv;
        }
    }
}

// ---- bnfix2: in-place BN+ReLU on 2-plane tiles (y1) ----
__global__ __launch_bounds__(256) void bnfix2(u16* __restrict__ yt, int KT,
                                              const float2* __restrict__ ash) {
    const int kt = blockIdx.x, nt = blockIdx.y, b = blockIdx.z;
    u16* tb = yt + ((size_t)((b * 32 + nt) * KT + kt) << 13);
    const int n = threadIdx.x & 127, kh = threadIdx.x >> 7;
#pragma unroll
    for (int q = 0; q < 2; ++q) {
        const int kot = kh * 2 + q;
        u16* ph = tb + kot * 1024 + n * 8;
        uint4 H  = *(uint4*)ph;
        uint4 Mv = *(uint4*)(ph + 4096);
        u32 hw[4] = {H.x, H.y, H.z, H.w};
        u32 mw[4] = {Mv.x, Mv.y, Mv.z, Mv.w};
        u32 oh[4], om[4];
#pragma unroll
        for (int wi = 0; wi < 4; ++wi) {
            u32 uh2[2], um2[2];
#pragma unroll
            for (int e = 0; e < 2; ++e) {
                const u32 hb = e ? (hw[wi] & 0xFFFF0000u) : (hw[wi] << 16);
                const u32 mb = e ? (mw[wi] & 0xFFFF0000u) : (mw[wi] << 16);
                const float x = __uint_as_float(hb) + __uint_as_float(mb);
                const int k = kt * 32 + kot * 8 + wi * 2 + e;
                const float2 a = ash[k];
                const float y = fmaxf(fmaf(a.x, x, a.y), 0.f);
                const u32 uy = __float_as_uint(y) + 0x8000u;
                const float r1 = y - __uint_as_float(uy & 0xFFFF0000u);
                uh2[e] = uy;
                um2[e] = __float_as_uint(r1) + 0x8000u;
            }
            oh[wi] = pk(uh2[0], uh2[1]);
            om[wi] = pk(um2[0], um2[1]);
        }
        *(uint4*)ph          = make_uint4(oh[0], oh[1], oh[2], oh[3]);
        *(uint4*)(ph + 4096) = make_uint4(om[0], om[1], om[2], om[3]);
    }
}

// ---- bnfix1: in-place BN+ReLU on single-plane bf16 tiles (y2) ----
__global__ __launch_bounds__(256) void bnfix1(u16* __restrict__ yt, int KT,
                                              const float2* __restrict__ ash) {
    const int kt = blockIdx.x, nt = blockIdx.y, b = blockIdx.z;
    u16* tb = yt + ((size_t)((b * 32 + nt) * KT + kt) << 12);
    const int n = threadIdx.x & 127, kh = threadIdx.x >> 7;
#pragma unroll
    for (int q = 0; q < 2; ++q) {
        const int kot = kh * 2 + q;
        u16* ph = tb + kot * 1024 + n * 8;
        uint4 H = *(uint4*)ph;
        u32 hw[4] = {H.x, H.y, H.z, H.w};
        u32 oh[4];
#pragma unroll
        for (int wi = 0; wi < 4; ++wi) {
            u32 uh2[2];
#pragma unroll
            for (int e = 0; e < 2; ++e) {
                const u32 hb = e ? (hw[wi] & 0xFFFF0000u) : (hw[wi] << 16);
                const float x = __uint_as_float(hb);
                const int k = kt * 32 + kot * 8 + wi * 2 + e;
                const float2 a = ash[k];
                const float y = fmaxf(fmaf(a.x, x, a.y), 0.f);
                uh2[e] = __float_as_uint(y) + 0x8000u;
            }
            oh[wi] = pk(uh2[0], uh2[1]);
        }
        *(uint4*)ph = make_uint4(oh[0], oh[1], oh[2], oh[3]);
    }
}

// ================= L1 GEMM (fp32 B, 3-product, 128^2, dbuf; writes 2-plane y1) =================
__global__ __launch_bounds__(256)
void gemm_L1(const u16* __restrict__ Wimg, int KT, int Kact, int M_,
             const float* __restrict__ bias, const float* __restrict__ X,
             u16* __restrict__ Yt, int YKT,
             float* __restrict__ psum, float* __restrict__ psq)
{
    __shared__ __align__(16) u16 As_[2 * 8192];
    __shared__ __align__(16) u16 Bs_[2 * 8192];
    const int tid = threadIdx.x;
    const int lane = tid & 63, wid = tid >> 6;
    const int l15 = lane & 15, l4 = lane >> 4;
    const int wm = wid >> 1, wn = wid & 1;
    const int nt = blockIdx.x, mtb = blockIdx.y, b = blockIdx.z;
    const int m0 = mtb * 128, n0 = nt * 128;
    const int nb = tid & 127, kh = tid >> 7;
    f32x4 acc[4][4];
#pragma unroll
    for (int i = 0; i < 4; ++i)
#pragma unroll
        for (int j = 0; j < 4; ++j) acc[i][j] = (f32x4){0.f, 0.f, 0.f, 0.f};
    const u16* wtile = Wimg + ((size_t)mtb * KT << 13);
    const int afo = l4 * 1024 + (wm * 64 + l15) * 8;
    const int bfo = l4 * 1024 + (wn * 64 + l15) * 8;
    float xr[16];

#define L1_STAGE_A(kt, buf)                                                       \
    {                                                                             \
        const u16* g_ = wtile + ((size_t)(kt) << 13);                             \
        u16* l_ = As_ + ((buf) << 13);                                            \
        _Pragma("unroll")                                                         \
        for (int i_ = 0; i_ < 4; ++i_)                                            \
            gload_lds16(g_ + (wid * 4 + i_) * 512 + lane * 8,                     \
                        l_ + (wid * 4 + i_) * 512);                               \
    }
#define L1_READ_B(kt)                                                             \
    {                                                                             \
        const int kb_ = (kt) * 32 + kh * 16;                                      \
        const float* src_ = X + ((size_t)b * Kact + kb_) * NPTS + n0 + nb;        \
        _Pragma("unroll")                                                         \
        for (int j_ = 0; j_ < 16; ++j_)                                           \
            xr[j_] = (kb_ + j_ < Kact) ? src_[(size_t)j_ * NPTS] : 0.f;           \
    }
#define L1_WRITE_B(buf)                                                           \
    {                                                                             \
        u32 hh_[16], mm_[16];                                                     \
        _Pragma("unroll")                                                         \
        for (int j_ = 0; j_ < 16; ++j_) {                                         \
            const float x_ = xr[j_];                                              \
            const u32 u_ = __float_as_uint(x_);                                   \
            const u32 uh_ = u_ + 0x8000u;                                         \
            const float r1_ = x_ - __uint_as_float(uh_ & 0xFFFF0000u);            \
            hh_[j_] = uh_;                                                        \
            mm_[j_] = __float_as_uint(r1_) + 0x8000u;                             \
        }                                                                         \
        u16* bb_ = Bs_ + ((buf) << 13);                                           \
        _Pragma("unroll")                                                         \
        for (int q_ = 0; q_ < 2; ++q_) {                                          \
            uint4 wh_, wm_;                                                       \
            wh_.x = pk(hh_[q_*8+0], hh_[q_*8+1]); wh_.y = pk(hh_[q_*8+2], hh_[q_*8+3]); \
            wh_.z = pk(hh_[q_*8+4], hh_[q_*8+5]); wh_.w = pk(hh_[q_*8+6], hh_[q_*8+7]); \
            wm_.x = pk(mm_[q_*8+0], mm_[q_*8+1]); wm_.y = pk(mm_[q_*8+2], mm_[q_*8+3]); \
            wm_.z = pk(mm_[q_*8+4], mm_[q_*8+5]); wm_.w = pk(mm_[q_*8+6], mm_[q_*8+7]); \
            const int kot_ = kh * 2 + q_;                                         \
            *(uint4*)(bb_ + kot_ * 1024 + nb * 8)        = wh_;                   \
            *(uint4*)(bb_ + 4096 + kot_ * 1024 + nb * 8) = wm_;                   \
        }                                                                         \
    }
#define L1_COMPUTE(buf)                                                           \
    {                                                                             \
        const u16* A_ = As_ + ((buf) << 13);                                      \
        const u16* B_ = Bs_ + ((buf) << 13);                                      \
        short8 ah_[4], am_[4];                                                    \
        _Pragma("unroll")                                                         \
        for (int mf_ = 0; mf_ < 4; ++mf_) {                                       \
            ah_[mf_] = *(const short8*)(A_ + afo + mf_ * 128);                    \
            am_[mf_] = *(const short8*)(A_ + 4096 + afo + mf_ * 128);             \
        }                                                                         \
        _Pragma("unroll")                                                         \
        for (int nf_ = 0; nf_ < 4; ++nf_) {                                       \
            const short8 bh_ = *(const short8*)(B_ + bfo + nf_ * 128);            \
            const short8 bm_ = *(const short8*)(B_ + 4096 + bfo + nf_ * 128);     \
            _Pragma("unroll")                                                     \
            for (int mf_ = 0; mf_ < 4; ++mf_)                                     \
                acc[mf_][nf_] = MFM(ah_[mf_], bh_, acc[mf_][nf_]);                \
            _Pragma("unroll")                                                     \
            for (int mf_ = 0; mf_ < 4; ++mf_)                                     \
                acc[mf_][nf_] = MFM(ah_[mf_], bm_, acc[mf_][nf_]);                \
            _Pragma("unroll")                                                     \
            for (int mf_ = 0; mf_ < 4; ++mf_)                                     \
                acc[mf_][nf_] = MFM(am_[mf_], bh_, acc[mf_][nf_]);                \
        }                                                                         \
    }

    int o = 0;
    L1_READ_B(0);
    L1_STAGE_A(0, 0);
    L1_WRITE_B(0);
    __syncthreads();
    for (int kt = 0; kt < KT; ++kt) {
        if (kt + 1 < KT) {
            L1_READ_B(kt + 1);
            L1_STAGE_A(kt + 1, o ^ 1);
        }
        L1_COMPUTE(o);
        if (kt + 1 < KT) { L1_WRITE_B(o ^ 1); }
        __syncthreads();
        o ^= 1;
    }

    u16* ytb = Yt + ((size_t)((b * 32 + nt) * YKT) << 13);
#pragma unroll
    for (int mf = 0; mf < 4; ++mf) {
        const int kb = m0 + wm * 64 + mf * 16 + l4 * 4;
        float v4[4][4];
#pragma unroll
        for (int r = 0; r < 4; ++r) {
            const int m = kb + r;
            const float bvv = bias[m];
            float rs = 0.f, rq = 0.f;
#pragma unroll
            for (int nf = 0; nf < 4; ++nf) {
                const float v = acc[mf][nf][r] + bvv;
                v4[r][nf] = v; rs += v; rq = fmaf(v, v, rq);
            }
#pragma unroll
            for (int s = 1; s < 16; s <<= 1) {
                rs += __shfl_xor(rs, s);
                rq += __shfl_xor(rq, s);
            }
            if (l15 == 0) {
                const int slot = (b * 32 + nt) * 2 + wn;
                psum[(size_t)slot * M_ + m] = rs;
                psq[(size_t)slot * M_ + m]  = rq;
            }
        }
        {
            const int ktp = kb >> 5, kot = (kb >> 3) & 3, j0 = kb & 7;
            u16* dt = ytb + ((size_t)ktp << 13) + kot * 1024 + j0;
#pragma unroll
            for (int nf = 0; nf < 4; ++nf) {
                const int nwi = wn * 64 + nf * 16 + l15;
                u32 uh[4], um[4];
#pragma unroll
                for (int r = 0; r < 4; ++r) {
                    const float v = v4[r][nf];
                    const u32 a = __float_as_uint(v) + 0x8000u;
                    const float r1 = v - __uint_as_float(a & 0xFFFF0000u);
                    uh[r] = a;
                    um[r] = __float_as_uint(r1) + 0x8000u;
                }
                uint2 wh2; wh2.x = pk(uh[0], uh[1]); wh2.y = pk(uh[2], uh[3]);
                uint2 wm2; wm2.x = pk(um[0], um[1]); wm2.y = pk(um[2], um[3]);
                *(uint2*)(dt + nwi * 8)        = wh2;
                *(uint2*)(dt + 4096 + nwi * 8) = wm2;
            }
        }
    }
}

// ================= 8-phase 256^2 kernels =================
#define G8_PARAMS                                                                 \
    const u16* __restrict__ Wimg, int KT, int M_,                                 \
    const float* __restrict__ bias,                                               \
    const u16* __restrict__ Bt,                                                   \
    u16* __restrict__ Yt, int YKT,                                                \
    float* __restrict__ psum, float* __restrict__ psq,                            \
    float* __restrict__ pmax, float* __restrict__ pmin

#define STAGE_A8(kt, buf)                                                         \
    {                                                                             \
        const u16* g_ = wtile + ((size_t)(kt) << 14);                             \
        u16* l_ = As_ + ((buf) << 14);                                            \
        _Pragma("unroll")                                                         \
        for (int i_ = 0; i_ < 4; ++i_)                                            \
            gload_lds16(g_ + (wid * 4 + i_) * 512 + lane * 8,                     \
                        l_ + (wid * 4 + i_) * 512);                               \
    }
#define STAGE_B8_3P(kt, buf)                                                      \
    {                                                                             \
        const u16* g_ = btw + ((size_t)(kt) << 13);                               \
        u16* l_ = Bs_ + ((buf) << 14) + (wm << 13);                               \
        _Pragma("unroll")                                                         \
        for (int i_ = 0; i_ < 4; ++i_)                                            \
            gload_lds16(g_ + (wn * 4 + i_) * 512 + lane * 8,                      \
                        l_ + (wn * 4 + i_) * 512);                                \
    }
#define STAGE_B8_2P(kt, buf)                                                      \
    {                                                                             \
        const u16* g_ = btw + ((size_t)(kt) << 12);                               \
        u16* l_ = Bs_ + ((buf) << 13) + (wm << 12);                               \
        _Pragma("unroll")                                                         \
        for (int i_ = 0; i_ < 2; ++i_)                                            \
            gload_lds16(g_ + (wn * 2 + i_) * 512 + lane * 8,                      \
                        l_ + (wn * 2 + i_) * 512);                                \
    }

#define MFMA_BLK(q, a0, a1, B0, B1, B2, B3)                                       \
        acc[2*(q)][0]   = MFM(a0, B0, acc[2*(q)][0]);                             \
        acc[2*(q)+1][0] = MFM(a1, B0, acc[2*(q)+1][0]);                           \
        acc[2*(q)][1]   = MFM(a0, B1, acc[2*(q)][1]);                             \
        acc[2*(q)+1][1] = MFM(a1, B1, acc[2*(q)+1][1]);                           \
        acc[2*(q)][2]   = MFM(a0, B2, acc[2*(q)][2]);                             \
        acc[2*(q)+1][2] = MFM(a1, B2, acc[2*(q)+1][2]);                           \
        acc[2*(q)][3]   = MFM(a0, B3, acc[2*(q)][3]);                             \
        acc[2*(q)+1][3] = MFM(a1, B3, acc[2*(q)+1][3]);

// ---- L2: 2 half-phases/kt, 48 MFMA/phase (3-product). Stage A+B at p0; vmcnt at p1. ----
#define PHASE2_3P(p, CUR, NXT, kt)                                                \
    {                                                                             \
        const u16* A_ = As_ + ((CUR) << 14);                                      \
        short8 a0h = *(const short8*)(A_ + aof + (4 * (p) + 0) * 128);            \
        short8 a1h = *(const short8*)(A_ + aof + (4 * (p) + 1) * 128);            \
        short8 a2h = *(const short8*)(A_ + aof + (4 * (p) + 2) * 128);            \
        short8 a3h = *(const short8*)(A_ + aof + (4 * (p) + 3) * 128);            \
        short8 a0m = *(const short8*)(A_ + 8192 + aof + (4 * (p) + 0) * 128);     \
        short8 a1m = *(const short8*)(A_ + 8192 + aof + (4 * (p) + 1) * 128);     \
        short8 a2m = *(const short8*)(A_ + 8192 + aof + (4 * (p) + 2) * 128);     \
        short8 a3m = *(const short8*)(A_ + 8192 + aof + (4 * (p) + 3) * 128);     \
        if ((p) == 0) {                                                           \
            const u16* B_ = Bs_ + ((CUR) << 14) + bof;                            \
            bh0 = *(const short8*)(B_);                                           \
            bh1 = *(const short8*)(B_ + 128);                                     \
            bh2 = *(const short8*)(B_ + 256);                                     \
            bh3 = *(const short8*)(B_ + 384);                                     \
            bm0 = *(const short8*)(B_ + 4096);                                    \
            bm1 = *(const short8*)(B_ + 4096 + 128);                              \
            bm2 = *(const short8*)(B_ + 4096 + 256);                              \
            bm3 = *(const short8*)(B_ + 4096 + 384);                              \
        }                                                                         \
        if ((p) == 0 && (kt) + 1 < KT) {                                          \
            STAGE_A8((kt) + 1, NXT);                                              \
            STAGE_B8_3P((kt) + 1, NXT);                                           \
        }                                                                         \
        if ((p) == 1) { asm volatile("s_waitcnt vmcnt(0)" ::: "memory"); }        \
        __builtin_amdgcn_sched_barrier(0);                                        \
        __builtin_amdgcn_s_barrier();                                             \
        asm volatile("s_waitcnt lgkmcnt(0)" ::: "memory");                        \
        __builtin_amdgcn_sched_barrier(0);                                        \
        __builtin_amdgcn_s_setprio(1);                                            \
        MFMA_BLK(2*(p),     a0h, a1h, bh0, bh1, bh2, bh3)                         \
        MFMA_BLK(2*(p) + 1, a2h, a3h, bh0, bh1, bh2, bh3)                         \
        MFMA_BLK(2*(p),     a0h, a1h, bm0, bm1, bm2, bm3)                         \
        MFMA_BLK(2*(p) + 1, a2h, a3h, bm0, bm1, bm2, bm3)                         \
        MFMA_BLK(2*(p),     a0m, a1m, bh0, bh1, bh2, bh3)                         \
        MFMA_BLK(2*(p) + 1, a2m, a3m, bh0, bh1, bh2, bh3)                         \
        __builtin_amdgcn_s_setprio(0);                                            \
    }

// ---- L3: 2 half-phases/kt, 32 MFMA/phase (2-product). Stage A+B at p0; vmcnt at p1. ----
#define PHASE2_2P(p, CUR, NXT, kt)                                                \
    {                                                                             \
        const u16* A_ = As_ + ((CUR) << 14);                                      \
        short8 a0h = *(const short8*)(A_ + aof + (4 * (p) + 0) * 128);            \
        short8 a1h = *(const short8*)(A_ + aof + (4 * (p) + 1) * 128);            \
        short8 a2h = *(const short8*)(A_ + aof + (4 * (p) + 2) * 128);            \
        short8 a3h = *(const short8*)(A_ + aof + (4 * (p) + 3) * 128);            \
        short8 a0m = *(const short8*)(A_ + 8192 + aof + (4 * (p) + 0) * 128);     \
        short8 a1m = *(const short8*)(A_ + 8192 + aof + (4 * (p) + 1) * 128);     \
        short8 a2m = *(const short8*)(A_ + 8192 + aof + (4 * (p) + 2) * 128);     \
        short8 a3m = *(const short8*)(A_ + 8192 + aof + (4 * (p) + 3) * 128);     \
        if ((p) == 0) {                                                           \
            const u16* B_ = Bs_ + ((CUR) << 13) + bof;                            \
            bh0 = *(const short8*)(B_);                                           \
            bh1 = *(const short8*)(B_ + 128);                                     \
            bh2 = *(const short8*)(B_ + 256);                                     \
            bh3 = *(const short8*)(B_ + 384);                                     \
        }                                                                         \
        if ((p) == 0 && (kt) + 1 < KT) {                                          \
            STAGE_A8((kt) + 1, NXT);                                              \
            STAGE_B8_2P((kt) + 1, NXT);                                           \
        }                                                                         \
        if ((p) == 1) { asm volatile("s_waitcnt vmcnt(0)" ::: "memory"); }        \
        __builtin_amdgcn_sched_barrier(0);                                        \
        __builtin_amdgcn_s_barrier();                                             \
        asm volatile("s_waitcnt lgkmcnt(0)" ::: "memory");                        \
        __builtin_amdgcn_sched_barrier(0);                                        \
        __builtin_amdgcn_s_setprio(1);                                            \
        MFMA_BLK(2*(p),     a0h, a1h, bh0, bh1, bh2, bh3)                         \
        MFMA_BLK(2*(p) + 1, a2h, a3h, bh0, bh1, bh2, bh3)                         \
        MFMA_BLK(2*(p),     a0m, a1m, bh0, bh1, bh2, bh3)                         \
        MFMA_BLK(2*(p) + 1, a2m, a3m, bh0, bh1, bh2, bh3)                         \
        __builtin_amdgcn_s_setprio(0);                                            \
    }

#define G8_EPILOGUE(STOREP, MAXMIN)                                               \
    _Pragma("unroll")                                                             \
    for (int mf = 0; mf < 8; ++mf) {                                              \
        const int mbase = mtb * 256 + wm * 128 + mf * 16 + l4 * 4;                \
        float v4[4][4];                                                           \
        _Pragma("unroll")                                                         \
        for (int r = 0; r < 4; ++r) {                                             \
            const int m = mbase + r;                                              \
            const float bvv = bias[m];                                            \
            float rs = 0.f, rq = 0.f;                                             \
            _Pragma("unroll")                                                     \
            for (int nf = 0; nf < 4; ++nf) {                                      \
                const float v = acc[mf][nf][r] + bvv;                             \
                v4[r][nf] = v; rs += v; rq = fmaf(v, v, rq);                      \
            }                                                                     \
            float mx = 0.f, mn = 0.f;                                             \
            if (MAXMIN) {                                                         \
                mx = fmaxf(fmaxf(v4[r][0], v4[r][1]), fmaxf(v4[r][2], v4[r][3])); \
                mn = fminf(fminf(v4[r][0], v4[r][1]), fminf(v4[r][2], v4[r][3])); \
            }                                                                     \
            _Pragma("unroll")                                                     \
            for (int s = 1; s < 16; s <<= 1) {                                    \
                rs += __shfl_xor(rs, s);                                          \
                rq += __shfl_xor(rq, s);                                          \
                if (MAXMIN) {                                                     \
                    mx = fmaxf(mx, __shfl_xor(mx, s));                            \
                    mn = fminf(mn, __shfl_xor(mn, s));                            \
                }                                                                 \
            }                                                                     \
            if (l15 == 0) {                                                       \
                const int slot = (b * 16 + ntb) * 4 + wn;                         \
                psum[(size_t)slot * M_ + m] = rs;                                 \
                psq[(size_t)slot * M_ + m]  = rq;                                 \
                if (MAXMIN) {                                                     \
                    pmax[((size_t)b * M_ + m) * 64 + ntb * 4 + wn] = mx;          \
                    pmin[((size_t)b * M_ + m) * 64 + ntb * 4 + wn] = mn;          \
                }                                                                 \
            }                                                                     \
        }                                                                         \
        if (STOREP) {                                                             \
            const int ktp = mbase >> 5, kot = (mbase >> 3) & 3, j0 = mbase & 7;   \
            u16* dt = ytb + ((size_t)ktp << 12) + kot * 1024 + j0;                \
            _Pragma("unroll")                                                     \
            for (int nf = 0; nf < 4; ++nf) {                                      \
                const int nwi = (wn & 1) * 64 + nf * 16 + l15;                    \
                u32 uh[4];                                                        \
                _Pragma("unroll")                                                 \
                for (int r = 0; r < 4; ++r)                                       \
                    uh[r] = __float_as_uint(v4[r][nf]) + 0x8000u;                 \
                uint2 wh2; wh2.x = pk(uh[0], uh[1]); wh2.y = pk(uh[2], uh[3]);    \
                *(uint2*)(dt + nwi * 8) = wh2;                                    \
            }                                                                     \
        }                                                                         \
    }

// L2: 3-product, 2-plane B (y1); 2 half-phases/kt; stores y2 single-plane
__global__ __launch_bounds__(512) void gemm8p_L2(G8_PARAMS)
{
    __shared__ __align__(16) u16 As_[2 * 16384];
    __shared__ __align__(16) u16 Bs_[2 * 16384];
    const int tid = threadIdx.x;
    const int lane = tid & 63, wid = tid >> 6;
    const int l15 = lane & 15, l4 = lane >> 4;
    const int wm = wid >> 2, wn = wid & 3;
    const int ntb = blockIdx.x, mtb = blockIdx.y, b = blockIdx.z;
    f32x4 acc[8][4];
#pragma unroll
    for (int i = 0; i < 8; ++i)
#pragma unroll
        for (int j = 0; j < 4; ++j) acc[i][j] = (f32x4){0.f, 0.f, 0.f, 0.f};
    const u16* wtile = Wimg + ((size_t)(mtb * KT) << 14);
    const u16* btw = Bt + ((size_t)((b * 32 + ntb * 2 + wm) * KT) << 13);
    const int aof = l4 * 2048 + (wm * 128 + l15) * 8;
    const int bof = (wn >> 1) * 8192 + l4 * 1024 + ((wn & 1) * 64 + l15) * 8;
    short8 bh0, bh1, bh2, bh3, bm0, bm1, bm2, bm3;
    STAGE_A8(0, 0)
    STAGE_B8_3P(0, 0)
    asm volatile("s_waitcnt vmcnt(0)" ::: "memory");
    __builtin_amdgcn_s_barrier();
    for (int kt = 0; kt < KT; kt += 2) {
        PHASE2_3P(0, 0, 1, kt) PHASE2_3P(1, 0, 1, kt)
        PHASE2_3P(0, 1, 0, kt + 1) PHASE2_3P(1, 1, 0, kt + 1)
    }
    u16* ytb = Yt + ((size_t)((b * 32 + ntb * 2 + (wn >> 1)) * YKT) << 12);
    G8_EPILOGUE(true, false)
}

// L3: 2-product, 1-plane B (y2); 2 half-phases/kt; max/min partials, no store
__global__ __launch_bounds__(512) void gemm8p_L3(G8_PARAMS)
{
    __shared__ __align__(16) u16 As_[2 * 16384];
    __shared__ __align__(16) u16 Bs_[2 * 8192];
    const int tid = threadIdx.x;
    const int lane = tid & 63, wid = tid >> 6;
    const int l15 = lane & 15, l4 = lane >> 4;
    const int wm = wid >> 2, wn = wid & 3;
    const int ntb = blockIdx.x, mtb = blockIdx.y, b = blockIdx.z;
    f32x4 acc[8][4];
#pragma unroll
    for (int i = 0; i < 8; ++i)
#pragma unroll
        for (int j = 0; j < 4; ++j) acc[i][j] = (f32x4){0.f, 0.f, 0.f, 0.f};
    const u16* wtile = Wimg + ((size_t)(mtb * KT) << 14);
    const u16* btw = Bt + ((size_t)((b * 32 + ntb * 2 + wm) * KT) << 12);
    const int aof = l4 * 2048 + (wm * 128 + l15) * 8;
    const int bof = (wn >> 1) * 4096 + l4 * 1024 + ((wn & 1) * 64 + l15) * 8;
    short8 bh0, bh1, bh2, bh3;
    STAGE_A8(0, 0)
    STAGE_B8_2P(0, 0)
    asm volatile("s_waitcnt vmcnt(0)" ::: "memory");
    __builtin_amdgcn_s_barrier();
    for (int kt = 0; kt < KT; kt += 2) {
        PHASE2_2P(0, 0, 1, kt) PHASE2_2P(1, 0, 1, kt)
        PHASE2_2P(0, 1, 0, kt + 1) PHASE2_2P(1, 1, 0, kt + 1)
    }
    u16* ytb = nullptr;
    G8_EPILOGUE(false, true)
}

// ---- stats stage 1: 16 chunks x (M/64) blocks; each block reduces 64 slots x 64 channels ----
__global__ __launch_bounds__(256) void stats1_k(const float* __restrict__ psum,
                                                const float* __restrict__ psq, int M_,
                                                double* __restrict__ dps,
                                                double* __restrict__ dpq)
{
    __shared__ double ds[4][64];
    __shared__ double dq[4][64];
    const int mloc = threadIdx.x & 63, q = threadIdx.x >> 6;
    const int m = blockIdx.x * 64 + mloc;
    const int ci = blockIdx.y;                 // chunk 0..15 (64 slots each)
    const int base = ci * 64 + q * 16;
    double s = 0.0, sq = 0.0;
    for (int sl = base; sl < base + 16; ++sl) {
        s  += (double)psum[(size_t)sl * M_ + m];
        sq += (double)psq[(size_t)sl * M_ + m];
    }
    ds[q][mloc] = s; dq[q][mloc] = sq;
    __syncthreads();
    if (threadIdx.x < 64) {
        dps[(size_t)ci * M_ + m] = ds[0][mloc] + ds[1][mloc] + ds[2][mloc] + ds[3][mloc];
        dpq[(size_t)ci * M_ + m] = dq[0][mloc] + dq[1][mloc] + dq[2][mloc] + dq[3][mloc];
    }
}

// ---- stats stage 2: combine 16 chunk partials -> BN scale/shift ----
__global__ __launch_bounds__(256) void stats2_k(const double* __restrict__ dps,
                                                const double* __restrict__ dpq, int M_,
                                                const float* __restrict__ g,
                                                const float* __restrict__ be,
                                                float2* __restrict__ ash)
{
    const int m = blockIdx.x * 256 + threadIdx.x;
    if (m >= M_) return;
    double S = 0.0, Q = 0.0;
    for (int ci = 0; ci < 16; ++ci) {
        S += dps[(size_t)ci * M_ + m];
        Q += dpq[(size_t)ci * M_ + m];
    }
    const double cnt = (double)NB * (double)NPTS;
    double mean = S / cnt;
    double var  = Q / cnt - mean * mean;
    if (var < 0.0) var = 0.0;
    const double a = (double)g[m] / sqrt(var + 1e-5);
    ash[m] = make_float2((float)a, (float)((double)be[m] - a * mean));
}

// ---- pool_k: per-(b,c) max/min select + BN-apply + ReLU -> h[b*1024+c] ----
__global__ __launch_bounds__(256) void pool_k(const float2* __restrict__ ash3,
                                              const float* __restrict__ pmax,
                                              const float* __restrict__ pmin,
                                              float* __restrict__ h)
{
    const int c = blockIdx.x * 256 + threadIdx.x;   // grid.x = 4
    const int b = blockIdx.y;                       // grid.y = 16
    const float2 a = ash3[c];
    const float* pxr = pmax + ((size_t)b * 1024 + c) * 64;
    const float* pnr = pmin + ((size_t)b * 1024 + c) * 64;
    float mxv = -FLT_BIG, mnv = FLT_BIG;
    for (int q = 0; q < 64; ++q) {
        mxv = fmaxf(mxv, pxr[q]);
        mnv = fminf(mnv, pnr[q]);
    }
    const float v = (a.x >= 0.f) ? fmaf(a.x, mxv, a.y) : fmaf(a.x, mnv, a.y);
    h[b * 1024 + c] = fmaxf(v, 0.f);
}

// ---- bn1d_k: final BN1d over batch ----
__global__ __launch_bounds__(256) void bn1d_k(const float* __restrict__ h,
                                              const float* __restrict__ g4,
                                              const float* __restrict__ be4,
                                              float* __restrict__ out)
{
    const int c = blockIdx.x * 256 + threadIdx.x;
    if (c >= 1024) return;
    float hv[NB];
    float s = 0.f;
    for (int b = 0; b < NB; ++b) {
        hv[b] = h[b * 1024 + c];
        s += hv[b];
    }
    const float mean = s * (1.f / NB);
    float var = 0.f;
    for (int b = 0; b < NB; ++b) { const float d = hv[b] - mean; var = fmaf(d, d, var); }
    var *= (1.f / NB);
    const double ai = (double)g4[c] / sqrt((double)var + 1e-5);
    for (int b = 0; b < NB; ++b)
        out[b * 1024 + c] = (float)(ai * ((double)hv[b] - (double)mean) + (double)be4[c]);
}

extern "C" void kernel_launch(void* const* d_in, const int* in_sizes, int n_in,
                              void* d_out, int out_size, void* d_ws, size_t ws_size,
                              hipStream_t stream) {
    const float* xyz = (const float*)d_in[0];
    const float* W1  = (const float*)d_in[1];
    const float* b1  = (const float*)d_in[2];
    const float* g1  = (const float*)d_in[3];
    const float* be1 = (const float*)d_in[4];
    const float* W2  = (const float*)d_in[5];
    const float* b2  = (const float*)d_in[6];
    const float* g2  = (const float*)d_in[7];
    const float* be2 = (const float*)d_in[8];
    const float* W3  = (const float*)d_in[9];
    const float* b3  = (const float*)d_in[10];
    const float* g3  = (const float*)d_in[11];
    const float* be3 = (const float*)d_in[12];
    const float* g4  = (const float*)d_in[13];
    const float* be4 = (const float*)d_in[14];

    float* ws = (float*)d_ws;
    u16*   y1t = (u16*)(ws + OFF_Y1T);
    u16*   y2t = (u16*)(ws + OFF_Y2T);
    u16*   w1i = (u16*)(ws + OFF_W1I);
    u16*   w2i = (u16*)(ws + OFF_W2I);
    u16*   w3i = (u16*)(ws + OFF_W3I);
    float* ps  = ws + OFF_PS;
    float* pq  = ws + OFF_PQ;
    float* pmx = ws + OFF_PMX;
    float* pmn = ws + OFF_PMN;
    float2* ash = (float2*)(ws + OFF_ASH);
    float* h   = ws + OFF_H;
    double* dps = (double*)(ws + OFF_DPS);
    double* dpq = (double*)(ws + OFF_DPQ);
    float* out = (float*)d_out;

    // W images (2-plane): L1 128-chunks (42), L2 256-chunks (16), L3 256-chunks (64)
    prep_w<<<122, 256, 0, stream>>>(W1, W2, W3, w1i, w2i, w3i);

    // L1: 3-product fp32-B GEMM; writes pre-BN y1 2-plane tiles + stats
    gemm_L1<<<dim3(32, 2, 16), 256, 0, stream>>>(
        w1i, 21, 643, 256, b1, xyz, y1t, 8, ps, pq);
    stats1_k<<<dim3(4, 16), 256, 0, stream>>>(ps, pq, 256, dps, dpq);
    stats2_k<<<1, 256, 0, stream>>>(dps, dpq, 256, g1, be1, ash);
    bnfix2<<<dim3(8, 32, 16), 256, 0, stream>>>(y1t, 8, ash);

    // L2: 3-product 2-half-phase GEMM on 2-plane y1; writes pre-BN y2 SINGLE-plane tiles
    gemm8p_L2<<<dim3(16, 2, 16), 512, 0, stream>>>(
        w2i, 8, 512, b2, y1t, y2t, 16, ps, pq, nullptr, nullptr);
    stats1_k<<<dim3(8, 16), 256, 0, stream>>>(ps, pq, 512, dps, dpq);
    stats2_k<<<2, 256, 0, stream>>>(dps, dpq, 512, g2, be2, ash);
    bnfix1<<<dim3(16, 32, 16), 256, 0, stream>>>(y2t, 16, ash);

    // L3: 2-product 2-half-phase GEMM on 1-plane y2; stats + max/min partials (no y3)
    gemm8p_L3<<<dim3(16, 4, 16), 512, 0, stream>>>(
        w3i, 16, 1024, b3, y2t, nullptr, 0, ps, pq, pmx, pmn);

    // parallelized tail: L3 stats (2-stage) -> pool (64 blocks) -> BN1d
    stats1_k<<<dim3(16, 16), 256, 0, stream>>>(ps, pq, 1024, dps, dpq);
    stats2_k<<<4, 256, 0, stream>>>(dps, dpq, 1024, g3, be3, ash);
    pool_k<<<dim3(4, 16), 256, 0, stream>>>(ash, pmx, pmn, h);
    bn1d_k<<<4, 256, 0, stream>>>(h, g4, be4, out);
}